// Round 12
// baseline (159.483 us; speedup 1.0000x reference)
//
#include <hip/hip_runtime.h>
#include <hip/hip_bf16.h>

#define N_NODES 61440
#define NEDGE   491520
#define BATCH   2048
#define TT      30
#define C1      128
#define C2      512
#define C3      128
#define FCK     3840   // 128*30
#define MAXDEG  40     // Poisson(8) tail: P(deg>40) ~ 1e-11

typedef float floatx16 __attribute__((ext_vector_type(16)));
typedef __bf16 bfrag   __attribute__((ext_vector_type(8)));

static __device__ __forceinline__ unsigned short f2bf(float f) {
    unsigned u = __float_as_uint(f);
    u = u + 0x7fffu + ((u >> 16) & 1u);
    return (unsigned short)(u >> 16);
}
// packed f32x2 -> bf16x2 (RNE, bit-identical to f2bf pair)
static __device__ __forceinline__ unsigned cvtpk(float lo, float hi) {
    unsigned r;
    asm("v_cvt_pk_bf16_f32 %0, %1, %2" : "=v"(r) : "v"(lo), "v"(hi));
    return r;
}
static __device__ __forceinline__ bfrag ldf(const void* p) { return *(const bfrag*)p; }
#define MFMA(a, b, c) __builtin_amdgcn_mfma_f32_32x32x16_bf16(a, b, c, 0, 0, 0)

// ------------------------------------------- edges + weight repack (merged)
__global__ void k_edges_repack(
        const int* __restrict__ e32, int* __restrict__ cnt,
        unsigned short* __restrict__ eidx,
        const float* __restrict__ cw0, const float* __restrict__ dw0,
        const float* __restrict__ cw1, const float* __restrict__ dw1,
        const float* __restrict__ cw2, const float* __restrict__ dw2,
        const float* __restrict__ fcw,
        float* __restrict__ w0T, float* __restrict__ d0T,
        unsigned short* __restrict__ W1f, unsigned short* __restrict__ D1f,
        unsigned short* __restrict__ W2f, unsigned short* __restrict__ D2f,
        unsigned short* __restrict__ FCWf) {
    if (blockIdx.x < 1920) {
        int i = blockIdx.x * 256 + threadIdx.x;
        bool is64 = (e32[1] == 0) & (e32[3] == 0) & (e32[5] == 0) & (e32[7] == 0);
        int s, d;
        if (is64) { s = e32[2 * i]; d = e32[2 * (NEDGE + i)]; }
        else      { s = e32[i];     d = e32[NEDGE + i]; }
        int slot = atomicAdd(&cnt[d], 1);
        if (slot < MAXDEG) eidx[slot * N_NODES + d] = (unsigned short)s;
        return;
    }
    int i = (blockIdx.x - 1920) * 256 + threadIdx.x;
    if (i < 36 * 128) { int oc = i & 127, r = i >> 7; w0T[i] = cw0[oc * 36 + r]; }
    if (i < 12 * 128) { int oc = i & 127, ic = i >> 7; d0T[i] = dw0[oc * 12 + ic]; }
    if (i < 196608) {                       // W1f
        int pos = i & 511, f = i >> 9;
        int lane = pos >> 3, e = pos & 7;
        int oct = f & 15, q = (f >> 4) & 7, tap = f >> 7;
        int oc = oct * 32 + (lane & 31), ic = q * 16 + (lane >> 5) * 8 + e;
        W1f[i] = f2bf(cw1[(oc * 128 + ic) * 3 + tap]);
    } else if (i < 262144) {                // D1f
        int j = i - 196608;
        int pos = j & 511, f = j >> 9;
        int lane = pos >> 3, e = pos & 7;
        int oct = f & 15, q = f >> 4;
        int oc = oct * 32 + (lane & 31), ic = q * 16 + (lane >> 5) * 8 + e;
        D1f[j] = f2bf(dw1[oc * 128 + ic]);
    } else if (i < 458752) {                // W2f
        int j = i - 262144;
        int pos = j & 511, f = j >> 9;
        int lane = pos >> 3, e = pos & 7;
        int oct = f & 3, q = (f >> 2) & 31, tap = f >> 7;
        int oc = oct * 32 + (lane & 31), ic = q * 16 + (lane >> 5) * 8 + e;
        W2f[j] = f2bf(cw2[(oc * 512 + ic) * 3 + tap]);
    } else if (i < 524288) {                // D2f
        int j = i - 458752;
        int pos = j & 511, f = j >> 9;
        int lane = pos >> 3, e = pos & 7;
        int oct = f & 3, q = f >> 2;
        int oc = oct * 32 + (lane & 31), ic = q * 16 + (lane >> 5) * 8 + e;
        D2f[j] = f2bf(dw2[oc * 512 + ic]);
    } else if (i < 892928) {                // FCWf (240*3 frags)
        int j = i - 524288;
        int pos = j & 511, f = j >> 9;
        int lane = pos >> 3, e = pos & 7;
        int oct = f % 3, q = f / 3;
        int o = oct * 32 + (lane & 31);
        int k = q * 16 + (lane >> 5) * 8 + e;
        float v = (o < 72) ? fcw[o * 3840 + (k & 127) * 30 + (k >> 7)] : 0.f;
        FCWf[j] = f2bf(v);
    }
}

// ------------------------------------------------------------ TCN block 0
// Gather loop 4-way unrolled (r13 win: 4 independent neighbor chains in
// flight cut exposed L2 latency in the dominant loop).
__global__ __launch_bounds__(256) void k_block0(
        const float* __restrict__ x, const int* __restrict__ cnt,
        const unsigned short* __restrict__ eidx,
        const float* __restrict__ gw, const float* __restrict__ gb,
        const float* __restrict__ w0T, const float* __restrict__ d0T,
        const float* __restrict__ cb0, const float* __restrict__ db0,
        unsigned short* __restrict__ X1b) {
    __shared__ float wl[36 * 128];
    __shared__ float dl[12 * 128];
    __shared__ float cbl[128], dbl[128];
    __shared__ float gwl[144], gbl[12];
    __shared__ float aL[120][12];
    __shared__ float x0[4 * TT * 12];   // g values per node
    __shared__ __align__(16) unsigned short st[2][TT * 136];
    int tid = threadIdx.x;
    int b0 = blockIdx.x * 4;
    for (int i = tid; i < 36 * 128; i += 256) wl[i] = w0T[i];
    for (int i = tid; i < 12 * 128; i += 256) dl[i] = d0T[i];
    if (tid < 128) { cbl[tid] = cb0[tid]; dbl[tid] = db0[tid]; }
    if (tid < 144) gwl[tid] = gw[tid];
    if (tid >= 144 && tid < 156) gbl[tid - 144] = gb[tid - 144];

    // ---- gather: neighbor aggregation, 6 channels per thread half
    {
        int th = tid & 127;
        int grp = tid >> 7;
        if (th < 120) {
            size_t n = (size_t)b0 * TT + th;
            int ne = cnt[n]; if (ne > MAXDEG) ne = MAXDEG;
            float a0 = 0.f, a1 = 0.f, a2 = 0.f, a3 = 0.f, a4 = 0.f, a5 = 0.f;
            int j = 0;
            for (; j + 4 <= ne; j += 4) {
                int s0 = eidx[(j + 0) * N_NODES + n];
                int s1 = eidx[(j + 1) * N_NODES + n];
                int s2 = eidx[(j + 2) * N_NODES + n];
                int s3 = eidx[(j + 3) * N_NODES + n];
                float di0 = rsqrtf(1.0f + (float)cnt[s0]);
                float di1 = rsqrtf(1.0f + (float)cnt[s1]);
                float di2 = rsqrtf(1.0f + (float)cnt[s2]);
                float di3 = rsqrtf(1.0f + (float)cnt[s3]);
                const float2* xp0 = (const float2*)(x + (size_t)s0 * 12 + grp * 6);
                const float2* xp1 = (const float2*)(x + (size_t)s1 * 12 + grp * 6);
                const float2* xp2 = (const float2*)(x + (size_t)s2 * 12 + grp * 6);
                const float2* xp3 = (const float2*)(x + (size_t)s3 * 12 + grp * 6);
                float2 q00 = xp0[0], q01 = xp0[1], q02 = xp0[2];
                float2 q10 = xp1[0], q11 = xp1[1], q12 = xp1[2];
                float2 q20 = xp2[0], q21 = xp2[1], q22 = xp2[2];
                float2 q30 = xp3[0], q31 = xp3[1], q32 = xp3[2];
                a0 += di0 * q00.x; a1 += di0 * q00.y;
                a2 += di0 * q01.x; a3 += di0 * q01.y;
                a4 += di0 * q02.x; a5 += di0 * q02.y;
                a0 += di1 * q10.x; a1 += di1 * q10.y;
                a2 += di1 * q11.x; a3 += di1 * q11.y;
                a4 += di1 * q12.x; a5 += di1 * q12.y;
                a0 += di2 * q20.x; a1 += di2 * q20.y;
                a2 += di2 * q21.x; a3 += di2 * q21.y;
                a4 += di2 * q22.x; a5 += di2 * q22.y;
                a0 += di3 * q30.x; a1 += di3 * q30.y;
                a2 += di3 * q31.x; a3 += di3 * q31.y;
                a4 += di3 * q32.x; a5 += di3 * q32.y;
            }
            for (; j < ne; j++) {
                int s = eidx[j * N_NODES + n];
                float di = rsqrtf(1.0f + (float)cnt[s]);
                const float2* xp = (const float2*)(x + (size_t)s * 12 + grp * 6);
                float2 p0 = xp[0], p1 = xp[1], p2 = xp[2];
                a0 += di * p0.x; a1 += di * p0.y;
                a2 += di * p1.x; a3 += di * p1.y;
                a4 += di * p2.x; a5 += di * p2.y;
            }
            float* ap = &aL[th][grp * 6];
            ap[0] = a0; ap[1] = a1; ap[2] = a2; ap[3] = a3; ap[4] = a4; ap[5] = a5;
        }
    }
    __syncthreads();

    // ---- GCN finalize: u = dinv*a + dinv^2*x ; g = u gw^T + gb
    if (tid < 120) {
        size_t n = (size_t)b0 * TT + tid;
        float di = rsqrtf(1.0f + (float)cnt[n]);
        float d2 = di * di;
        const float4* xp = (const float4*)(x + n * 12);
        float u[12];
        #pragma unroll
        for (int q = 0; q < 3; q++) {
            float4 xv = xp[q];
            u[q*4+0] = di * aL[tid][q*4+0] + d2 * xv.x;
            u[q*4+1] = di * aL[tid][q*4+1] + d2 * xv.y;
            u[q*4+2] = di * aL[tid][q*4+2] + d2 * xv.z;
            u[q*4+3] = di * aL[tid][q*4+3] + d2 * xv.w;
        }
        #pragma unroll
        for (int c = 0; c < 12; c++) {
            float acc = gbl[c];
            #pragma unroll
            for (int j = 0; j < 12; j++) acc += u[j] * gwl[c * 12 + j];
            x0[tid * 12 + c] = acc;
        }
    }
    __syncthreads();

    // ---- conv 12->128 + down, per-thread over t
    int oc = tid & 127, half = tid >> 7;
    float cb = cbl[oc], db = dbl[oc];
    for (int bi = 0; bi < 2; bi++) {
        int bl = bi * 2 + half;
        const float* xb = x0 + bl * (TT * 12);
        float conv[TT], res[TT];
        #pragma unroll
        for (int t = 0; t < TT; t++) { conv[t] = 0.f; res[t] = 0.f; }
        #pragma unroll
        for (int ic = 0; ic < 12; ic++) {
            float w0v = wl[(ic * 3 + 0) * 128 + oc];
            float w1v = wl[(ic * 3 + 1) * 128 + oc];
            float w2v = wl[(ic * 3 + 2) * 128 + oc];
            float dv  = dl[ic * 128 + oc];
            #pragma unroll
            for (int t = 0; t < TT; t++) {
                float xv = xb[t * 12 + ic];
                conv[t] += w2v * xv;
                if (t + 1 < TT) conv[t + 1] += w1v * xv;
                if (t + 2 < TT) conv[t + 2] += w0v * xv;
                res[t] += dv * xv;
            }
        }
        #pragma unroll
        for (int t = 0; t < TT; t++) {
            float o1 = fmaxf(conv[t] + cb, 0.f);
            st[half][t * 136 + oc] = f2bf(fmaxf(o1 + res[t] + db, 0.f));
        }
        __syncthreads();
        for (int idx = tid; idx < 2 * TT * 16; idx += 256) {
            int h = idx / (TT * 16), rem = idx - h * (TT * 16);
            int row = rem >> 4, seg = rem & 15;
            *(uint4*)(X1b + (size_t)((b0 + bi * 2 + h) * TT + row) * 128 + seg * 8) =
                *(const uint4*)(&st[h][row * 136 + seg * 8]);
        }
        __syncthreads();
    }
}

// -------------------------------------------------- TCN blocks 1+2, MFMA
// r11 state (78.5 us): round-0 structure + cvtpk write-out + bias-folded
// acc init + hoisted first weight prefetches.  Structural equilibrium:
// register pin (wf[2][16] -> ~240 regs/wave -> 2 waves/SIMD) and LDS pin
// (80 KB -> 2 blocks/CU) both bind; 7 structural escapes measured worse.
__global__ __launch_bounds__(256, 2) void k_tcn12(
        const unsigned short* __restrict__ X1b,
        const unsigned short* __restrict__ W1f, const unsigned short* __restrict__ D1f,
        const float* __restrict__ cb1, const float* __restrict__ db1,
        const unsigned short* __restrict__ W2f, const unsigned short* __restrict__ D2f,
        const float* __restrict__ cb2, const float* __restrict__ db2,
        unsigned short* __restrict__ X3b) {
    __shared__ __align__(16) unsigned short X1l[61 * 136];  // rows 0..59 data, 60 = zeros
    __shared__ __align__(16) unsigned short X2l[61 * 520];
    const int tid  = threadIdx.x;
    const int lane = tid & 63;
    const int wave = tid >> 6;
    const int tcol = lane & 31;
    const int half = lane >> 5;
    const int b0 = blockIdx.x * 2;

    auto ldw1 = [&](bfrag* dst, int oct, int qc) {
        #pragma unroll
        for (int tap = 0; tap < 3; tap++)
            #pragma unroll
            for (int qq = 0; qq < 4; qq++)
                dst[tap * 4 + qq] =
                    ldf(W1f + (((tap * 8 + qc * 4 + qq) * 16 + oct) << 9) + lane * 8);
        #pragma unroll
        for (int qq = 0; qq < 4; qq++)
            dst[12 + qq] = ldf(D1f + (((qc * 4 + qq) * 16 + oct) << 9) + lane * 8);
    };
    auto ldw2 = [&](bfrag* dst, int oct, int qc) {
        #pragma unroll
        for (int tap = 0; tap < 3; tap++)
            #pragma unroll
            for (int qq = 0; qq < 4; qq++)
                dst[tap * 4 + qq] =
                    ldf(W2f + (((tap * 32 + qc * 4 + qq) * 4 + oct) << 9) + lane * 8);
        #pragma unroll
        for (int qq = 0; qq < 4; qq++)
            dst[12 + qq] = ldf(D2f + (((qc * 4 + qq) * 4 + oct) << 9) + lane * 8);
    };

    // first phase-1 weight prefetch: global->reg only, hoisted above staging
    bfrag wf[2][16];
    ldw1(wf[0], wave, 0);

    for (int idx = tid; idx < 960; idx += 256) {
        int row = idx >> 4, seg = idx & 15;
        *(uint4*)(X1l + row * 136 + seg * 8) =
            *(const uint4*)(X1b + ((size_t)(b0 * 30 + row) << 7) + seg * 8);
    }
    if (tid < 17) *(uint4*)(X1l + 60 * 136 + tid * 8) = make_uint4(0, 0, 0, 0);
    if (tid < 65) *(uint4*)(X2l + 60 * 520 + tid * 8) = make_uint4(0, 0, 0, 0);
    __syncthreads();

    // ---- phase 1: block1 (128->512, k=3 dil=3) + 1x1 down  -> X2l (bf16)
    {
        floatx16 accc[2], accd[2];
        #pragma unroll
        for (int s = 0; s < 8; s++) {
            const int qc = s & 1;
            const int oct = (s >> 1) * 4 + wave;
            if (qc == 0) {
                // bias-folded acc init (channel ocb+j lives at acc[gi*4+j])
                #pragma unroll
                for (int gi = 0; gi < 4; gi++) {
                    int ocb = oct * 32 + half * 4 + gi * 8;
                    float4 cbv = *(const float4*)(cb1 + ocb);
                    float4 dbv = *(const float4*)(db1 + ocb);
                    accc[0][gi*4+0] = cbv.x; accc[0][gi*4+1] = cbv.y;
                    accc[0][gi*4+2] = cbv.z; accc[0][gi*4+3] = cbv.w;
                    accd[0][gi*4+0] = dbv.x; accd[0][gi*4+1] = dbv.y;
                    accd[0][gi*4+2] = dbv.z; accd[0][gi*4+3] = dbv.w;
                    accc[1][gi*4+0] = cbv.x; accc[1][gi*4+1] = cbv.y;
                    accc[1][gi*4+2] = cbv.z; accc[1][gi*4+3] = cbv.w;
                    accd[1][gi*4+0] = dbv.x; accd[1][gi*4+1] = dbv.y;
                    accd[1][gi*4+2] = dbv.z; accd[1][gi*4+3] = dbv.w;
                }
            }
            if (s < 7)
                ldw1(wf[(s + 1) & 1], ((s + 1) >> 1) * 4 + wave, (s + 1) & 1);
            #pragma unroll
            for (int bl = 0; bl < 2; bl++) {
                bfrag bx[3][4];
                #pragma unroll
                for (int si = 0; si < 3; si++) {
                    int trow = tcol - si * 3;
                    const unsigned short* rp = ((unsigned)trow < 30u)
                        ? (X1l + (bl * 30 + trow) * 136) : (X1l + 60 * 136);
                    #pragma unroll
                    for (int qq = 0; qq < 4; qq++)
                        bx[si][qq] = ldf(rp + (qc * 4 + qq) * 16 + half * 8);
                }
                #pragma unroll
                for (int qq = 0; qq < 4; qq++) {
                    accc[bl] = MFMA(wf[s & 1][8 + qq],  bx[0][qq], accc[bl]);
                    accc[bl] = MFMA(wf[s & 1][4 + qq],  bx[1][qq], accc[bl]);
                    accc[bl] = MFMA(wf[s & 1][qq],      bx[2][qq], accc[bl]);
                    accd[bl] = MFMA(wf[s & 1][12 + qq], bx[0][qq], accd[bl]);
                }
            }
            if (qc == 1 && tcol < 30) {
                #pragma unroll
                for (int bl = 0; bl < 2; bl++) {
                    unsigned short* wp = X2l + (bl * 30 + tcol) * 520 + oct * 32 + half * 4;
                    #pragma unroll
                    for (int gi = 0; gi < 4; gi++) {
                        float v0 = fmaxf(fmaxf(accc[bl][gi*4+0], 0.f) + accd[bl][gi*4+0], 0.f);
                        float v1 = fmaxf(fmaxf(accc[bl][gi*4+1], 0.f) + accd[bl][gi*4+1], 0.f);
                        float v2 = fmaxf(fmaxf(accc[bl][gi*4+2], 0.f) + accd[bl][gi*4+2], 0.f);
                        float v3 = fmaxf(fmaxf(accc[bl][gi*4+3], 0.f) + accd[bl][gi*4+3], 0.f);
                        *(uint2*)(wp + gi * 8) = make_uint2(cvtpk(v0, v1), cvtpk(v2, v3));
                    }
                }
            }
        }
    }
    // phase-2 first weight prefetch: issue before the barrier (global->reg)
    bfrag wf2[2][16];
    ldw2(wf2[0], wave, 0);
    __syncthreads();

    // ---- phase 2: block2 (512->128, k=3 dil=9) + 1x1 down -> staged X3
    {
        const int oct = wave;
        floatx16 accc[2], accd[2];
        #pragma unroll
        for (int gi = 0; gi < 4; gi++) {
            int ocb = oct * 32 + half * 4 + gi * 8;
            float4 cbv = *(const float4*)(cb2 + ocb);
            float4 dbv = *(const float4*)(db2 + ocb);
            accc[0][gi*4+0] = cbv.x; accc[0][gi*4+1] = cbv.y;
            accc[0][gi*4+2] = cbv.z; accc[0][gi*4+3] = cbv.w;
            accd[0][gi*4+0] = dbv.x; accd[0][gi*4+1] = dbv.y;
            accd[0][gi*4+2] = dbv.z; accd[0][gi*4+3] = dbv.w;
            accc[1][gi*4+0] = cbv.x; accc[1][gi*4+1] = cbv.y;
            accc[1][gi*4+2] = cbv.z; accc[1][gi*4+3] = cbv.w;
            accd[1][gi*4+0] = dbv.x; accd[1][gi*4+1] = dbv.y;
            accd[1][gi*4+2] = dbv.z; accd[1][gi*4+3] = dbv.w;
        }
        #pragma unroll
        for (int qc = 0; qc < 8; qc++) {
            if (qc < 7) ldw2(wf2[(qc + 1) & 1], oct, qc + 1);
            #pragma unroll
            for (int bl = 0; bl < 2; bl++) {
                bfrag bx[3][4];
                #pragma unroll
                for (int si = 0; si < 3; si++) {
                    int trow = tcol - si * 9;
                    const unsigned short* rp = ((unsigned)trow < 30u)
                        ? (X2l + (bl * 30 + trow) * 520) : (X2l + 60 * 520);
                    #pragma unroll
                    for (int qq = 0; qq < 4; qq++)
                        bx[si][qq] = ldf(rp + (qc * 4 + qq) * 16 + half * 8);
                }
                #pragma unroll
                for (int qq = 0; qq < 4; qq++) {
                    accc[bl] = MFMA(wf2[qc & 1][8 + qq],  bx[0][qq], accc[bl]);
                    accc[bl] = MFMA(wf2[qc & 1][4 + qq],  bx[1][qq], accc[bl]);
                    accc[bl] = MFMA(wf2[qc & 1][qq],      bx[2][qq], accc[bl]);
                    accd[bl] = MFMA(wf2[qc & 1][12 + qq], bx[0][qq], accd[bl]);
                }
            }
        }
        if (tcol < 30) {   // stage into X1l area (free after phase 1)
            #pragma unroll
            for (int bl = 0; bl < 2; bl++) {
                unsigned short* wp = X1l + (bl * 30 + tcol) * 136 + oct * 32 + half * 4;
                #pragma unroll
                for (int gi = 0; gi < 4; gi++) {
                    float v0 = fmaxf(fmaxf(accc[bl][gi*4+0], 0.f) + accd[bl][gi*4+0], 0.f);
                    float v1 = fmaxf(fmaxf(accc[bl][gi*4+1], 0.f) + accd[bl][gi*4+1], 0.f);
                    float v2 = fmaxf(fmaxf(accc[bl][gi*4+2], 0.f) + accd[bl][gi*4+2], 0.f);
                    float v3 = fmaxf(fmaxf(accc[bl][gi*4+3], 0.f) + accd[bl][gi*4+3], 0.f);
                    *(uint2*)(wp + gi * 8) = make_uint2(cvtpk(v0, v1), cvtpk(v2, v3));
                }
            }
        }
    }
    __syncthreads();
    // coalesced flush: 60 rows x 256 B contiguous
    for (int idx = tid; idx < 960; idx += 256) {
        int row = idx >> 4, seg = idx & 15;
        *(uint4*)(X3b + ((size_t)(b0 * 30 + row) << 7) + seg * 8) =
            *(const uint4*)(X1l + row * 136 + seg * 8);
    }
}

// ------------------------------------------------------------- FC (MFMA)
// Round-12: grid 256 -> 512 (batch-group split 16 -> 32, 64 batches/WG).
// Old config was 1 block/CU = 1 wave/SIMD -- zero latency hiding for the
// 15-iter {LDS read + 3 L2 weight loads + 3 MFMA} chain and the staging.
// Now 2 blocks/CU, LDS 31.7 KB.  MFMA on waves 0-1 only (bl < 64); all 4
// waves stage.  Per-(o,b) partial computed by one wave in same ql order ->
// P bit-identical, same deterministic reduce.
__global__ __launch_bounds__(256) void k_fc_mfma(
        const unsigned short* __restrict__ X3b,
        const unsigned short* __restrict__ FCWf,
        unsigned short* __restrict__ P) {
    __shared__ __align__(16) unsigned short xt[64 * 248];   // 240 used + 8 pad
    const int tid  = threadIdx.x;
    const int lane = tid & 63;
    const int wave = tid >> 6;
    const int half = lane >> 5;
    const int bg = blockIdx.x & 31;
    const int kc = blockIdx.x >> 5;

    for (int idx = tid; idx < 64 * 32; idx += 256) {
        int row = idx >> 5, seg = idx & 31;
        if (seg < 30)
            *(uint4*)(xt + row * 248 + seg * 8) =
                *(const uint4*)(X3b + (size_t)(bg * 64 + row) * FCK + kc * 240 + seg * 8);
    }
    __syncthreads();

    if (wave < 2) {
        const int bl = wave * 32 + (lane & 31);
        floatx16 acc[3];
        acc[0] = 0; acc[1] = 0; acc[2] = 0;
        #pragma unroll
        for (int ql = 0; ql < 15; ql++) {
            int q = kc * 15 + ql;
            bfrag bx = ldf(xt + bl * 248 + ql * 16 + half * 8);
            #pragma unroll
            for (int oct = 0; oct < 3; oct++) {
                bfrag af = ldf(FCWf + ((q * 3 + oct) << 9) + lane * 8);
                acc[oct] = MFMA(af, bx, acc[oct]);
            }
        }
        unsigned short* base = P + (size_t)kc * 96 * BATCH;
        const int b = bg * 64 + bl;
        #pragma unroll
        for (int oct = 0; oct < 3; oct++)
            #pragma unroll
            for (int j = 0; j < 16; j++) {
                int o = oct * 32 + half * 4 + (j >> 2) * 8 + (j & 3);
                base[(size_t)o * BATCH + b] = f2bf(acc[oct][j]);
            }
    }
}

__global__ __launch_bounds__(256) void k_fc_reduce(
        const unsigned short* __restrict__ P, const float* __restrict__ fcb,
        float* __restrict__ out) {
    int j = blockIdx.x * blockDim.x + threadIdx.x;   // j = o*2048 + b, o<72
    int o = j >> 11, b = j & 2047;
    float acc = fcb[o];
    #pragma unroll
    for (int kc = 0; kc < 16; kc++) {
        unsigned u = P[((size_t)kc * 96 + o) * BATCH + b];
        acc += __uint_as_float(u << 16);
    }
    out[b * 72 + o] = acc;
}

// ---------------------------------------------------------------- launch

extern "C" void kernel_launch(void* const* d_in, const int* in_sizes, int n_in,
                              void* d_out, int out_size, void* d_ws, size_t ws_size,
                              hipStream_t stream) {
    const float* x   = (const float*)d_in[0];
    const int*   e32 = (const int*)  d_in[1];
    const float* gw  = (const float*)d_in[2];
    const float* gb  = (const float*)d_in[3];
    const float* cw0 = (const float*)d_in[4];
    const float* cb0 = (const float*)d_in[5];
    const float* dw0 = (const float*)d_in[6];
    const float* db0 = (const float*)d_in[7];
    const float* cw1 = (const float*)d_in[8];
    const float* cb1 = (const float*)d_in[9];
    const float* dw1 = (const float*)d_in[10];
    const float* db1 = (const float*)d_in[11];
    const float* cw2 = (const float*)d_in[12];
    const float* cb2 = (const float*)d_in[13];
    const float* dw2 = (const float*)d_in[14];
    const float* db2 = (const float*)d_in[15];
    const float* fcw = (const float*)d_in[16];
    const float* fcb = (const float*)d_in[17];

    char* w = (char*)d_ws;
    auto alloc = [&](size_t bytes) {
        char* p = w;
        w += (bytes + 255) & ~(size_t)255;
        return p;
    };
    int*            cnt  = (int*)           alloc(N_NODES * 4);
    unsigned short* eidx = (unsigned short*)alloc((size_t)N_NODES * MAXDEG * 2);
    float* w0T  = (float*)alloc(36 * 128 * 4);
    float* d0T  = (float*)alloc(12 * 128 * 4);
    unsigned short* W1f  = (unsigned short*)alloc(196608 * 2);
    unsigned short* D1f  = (unsigned short*)alloc(65536 * 2);
    unsigned short* W2f  = (unsigned short*)alloc(196608 * 2);
    unsigned short* D2f  = (unsigned short*)alloc(65536 * 2);
    unsigned short* FCWf = (unsigned short*)alloc(368640 * 2);
    unsigned short* X1b  = (unsigned short*)alloc((size_t)BATCH * TT * C1 * 2);
    unsigned short* X3b  = (unsigned short*)alloc((size_t)BATCH * TT * C3 * 2);
    unsigned short* P    = (unsigned short*)alloc((size_t)16 * 96 * BATCH * 2);

    hipMemsetAsync(cnt, 0, N_NODES * 4, stream);
    k_edges_repack<<<1920 + 3488, 256, 0, stream>>>(
        e32, cnt, eidx, cw0, dw0, cw1, dw1, cw2, dw2, fcw,
        w0T, d0T, W1f, D1f, W2f, D2f, FCWf);
    k_block0<<<BATCH / 4, 256, 0, stream>>>(x, cnt, eidx, gw, gb,
                                            w0T, d0T, cb0, db0, X1b);
    k_tcn12<<<BATCH / 2, 256, 0, stream>>>(X1b, W1f, D1f, cb1, db1,
                                           W2f, D2f, cb2, db2, X3b);
    k_fc_mfma<<<512, 256, 0, stream>>>(X3b, FCWf, P);
    k_fc_reduce<<<72 * BATCH / 256, 256, 0, stream>>>(P, fcb, (float*)d_out);
}

// Round 13
// 151.231 us; speedup vs baseline: 1.0546x; 1.0546x over previous
//
#include <hip/hip_runtime.h>
#include <hip/hip_bf16.h>

#define N_NODES 61440
#define NEDGE   491520
#define BATCH   2048
#define TT      30
#define C1      128
#define C2      512
#define C3      128
#define FCK     3840   // 128*30
#define MAXDEG  40     // Poisson(8) tail: P(deg>40) ~ 1e-11

typedef float floatx16 __attribute__((ext_vector_type(16)));
typedef __bf16 bfrag   __attribute__((ext_vector_type(8)));

static __device__ __forceinline__ unsigned short f2bf(float f) {
    unsigned u = __float_as_uint(f);
    u = u + 0x7fffu + ((u >> 16) & 1u);
    return (unsigned short)(u >> 16);
}
// packed f32x2 -> bf16x2 (RNE, bit-identical to f2bf pair)
static __device__ __forceinline__ unsigned cvtpk(float lo, float hi) {
    unsigned r;
    asm("v_cvt_pk_bf16_f32 %0, %1, %2" : "=v"(r) : "v"(lo), "v"(hi));
    return r;
}
static __device__ __forceinline__ bfrag ldf(const void* p) { return *(const bfrag*)p; }
#define MFMA(a, b, c) __builtin_amdgcn_mfma_f32_32x32x16_bf16(a, b, c, 0, 0, 0)

// ------------------------------------------- edges + weight repack (merged)
__global__ void k_edges_repack(
        const int* __restrict__ e32, int* __restrict__ cnt,
        unsigned short* __restrict__ eidx,
        const float* __restrict__ cw0, const float* __restrict__ dw0,
        const float* __restrict__ cw1, const float* __restrict__ dw1,
        const float* __restrict__ cw2, const float* __restrict__ dw2,
        const float* __restrict__ fcw,
        float* __restrict__ w0T, float* __restrict__ d0T,
        unsigned short* __restrict__ W1f, unsigned short* __restrict__ D1f,
        unsigned short* __restrict__ W2f, unsigned short* __restrict__ D2f,
        unsigned short* __restrict__ FCWf) {
    if (blockIdx.x < 1920) {
        int i = blockIdx.x * 256 + threadIdx.x;
        bool is64 = (e32[1] == 0) & (e32[3] == 0) & (e32[5] == 0) & (e32[7] == 0);
        int s, d;
        if (is64) { s = e32[2 * i]; d = e32[2 * (NEDGE + i)]; }
        else      { s = e32[i];     d = e32[NEDGE + i]; }
        int slot = atomicAdd(&cnt[d], 1);
        if (slot < MAXDEG) eidx[slot * N_NODES + d] = (unsigned short)s;
        return;
    }
    int i = (blockIdx.x - 1920) * 256 + threadIdx.x;
    if (i < 36 * 128) { int oc = i & 127, r = i >> 7; w0T[i] = cw0[oc * 36 + r]; }
    if (i < 12 * 128) { int oc = i & 127, ic = i >> 7; d0T[i] = dw0[oc * 12 + ic]; }
    if (i < 196608) {                       // W1f
        int pos = i & 511, f = i >> 9;
        int lane = pos >> 3, e = pos & 7;
        int oct = f & 15, q = (f >> 4) & 7, tap = f >> 7;
        int oc = oct * 32 + (lane & 31), ic = q * 16 + (lane >> 5) * 8 + e;
        W1f[i] = f2bf(cw1[(oc * 128 + ic) * 3 + tap]);
    } else if (i < 262144) {                // D1f
        int j = i - 196608;
        int pos = j & 511, f = j >> 9;
        int lane = pos >> 3, e = pos & 7;
        int oct = f & 15, q = f >> 4;
        int oc = oct * 32 + (lane & 31), ic = q * 16 + (lane >> 5) * 8 + e;
        D1f[j] = f2bf(dw1[oc * 128 + ic]);
    } else if (i < 458752) {                // W2f
        int j = i - 262144;
        int pos = j & 511, f = j >> 9;
        int lane = pos >> 3, e = pos & 7;
        int oct = f & 3, q = (f >> 2) & 31, tap = f >> 7;
        int oc = oct * 32 + (lane & 31), ic = q * 16 + (lane >> 5) * 8 + e;
        W2f[j] = f2bf(cw2[(oc * 512 + ic) * 3 + tap]);
    } else if (i < 524288) {                // D2f
        int j = i - 458752;
        int pos = j & 511, f = j >> 9;
        int lane = pos >> 3, e = pos & 7;
        int oct = f & 3, q = f >> 2;
        int oc = oct * 32 + (lane & 31), ic = q * 16 + (lane >> 5) * 8 + e;
        D2f[j] = f2bf(dw2[oc * 512 + ic]);
    } else if (i < 892928) {                // FCWf (240*3 frags)
        int j = i - 524288;
        int pos = j & 511, f = j >> 9;
        int lane = pos >> 3, e = pos & 7;
        int oct = f % 3, q = f / 3;
        int o = oct * 32 + (lane & 31);
        int k = q * 16 + (lane >> 5) * 8 + e;
        float v = (o < 72) ? fcw[o * 3840 + (k & 127) * 30 + (k >> 7)] : 0.f;
        FCWf[j] = f2bf(v);
    }
}

// ------------------------------------------------------------ TCN block 0
// Gather loop 4-way unrolled (proven win: 4 independent neighbor chains in
// flight cut exposed L2 latency in the dominant loop).
__global__ __launch_bounds__(256) void k_block0(
        const float* __restrict__ x, const int* __restrict__ cnt,
        const unsigned short* __restrict__ eidx,
        const float* __restrict__ gw, const float* __restrict__ gb,
        const float* __restrict__ w0T, const float* __restrict__ d0T,
        const float* __restrict__ cb0, const float* __restrict__ db0,
        unsigned short* __restrict__ X1b) {
    __shared__ float wl[36 * 128];
    __shared__ float dl[12 * 128];
    __shared__ float cbl[128], dbl[128];
    __shared__ float gwl[144], gbl[12];
    __shared__ float aL[120][12];
    __shared__ float x0[4 * TT * 12];   // g values per node
    __shared__ __align__(16) unsigned short st[2][TT * 136];
    int tid = threadIdx.x;
    int b0 = blockIdx.x * 4;
    for (int i = tid; i < 36 * 128; i += 256) wl[i] = w0T[i];
    for (int i = tid; i < 12 * 128; i += 256) dl[i] = d0T[i];
    if (tid < 128) { cbl[tid] = cb0[tid]; dbl[tid] = db0[tid]; }
    if (tid < 144) gwl[tid] = gw[tid];
    if (tid >= 144 && tid < 156) gbl[tid - 144] = gb[tid - 144];

    // ---- gather: neighbor aggregation, 6 channels per thread half
    {
        int th = tid & 127;
        int grp = tid >> 7;
        if (th < 120) {
            size_t n = (size_t)b0 * TT + th;
            int ne = cnt[n]; if (ne > MAXDEG) ne = MAXDEG;
            float a0 = 0.f, a1 = 0.f, a2 = 0.f, a3 = 0.f, a4 = 0.f, a5 = 0.f;
            int j = 0;
            for (; j + 4 <= ne; j += 4) {
                int s0 = eidx[(j + 0) * N_NODES + n];
                int s1 = eidx[(j + 1) * N_NODES + n];
                int s2 = eidx[(j + 2) * N_NODES + n];
                int s3 = eidx[(j + 3) * N_NODES + n];
                float di0 = rsqrtf(1.0f + (float)cnt[s0]);
                float di1 = rsqrtf(1.0f + (float)cnt[s1]);
                float di2 = rsqrtf(1.0f + (float)cnt[s2]);
                float di3 = rsqrtf(1.0f + (float)cnt[s3]);
                const float2* xp0 = (const float2*)(x + (size_t)s0 * 12 + grp * 6);
                const float2* xp1 = (const float2*)(x + (size_t)s1 * 12 + grp * 6);
                const float2* xp2 = (const float2*)(x + (size_t)s2 * 12 + grp * 6);
                const float2* xp3 = (const float2*)(x + (size_t)s3 * 12 + grp * 6);
                float2 q00 = xp0[0], q01 = xp0[1], q02 = xp0[2];
                float2 q10 = xp1[0], q11 = xp1[1], q12 = xp1[2];
                float2 q20 = xp2[0], q21 = xp2[1], q22 = xp2[2];
                float2 q30 = xp3[0], q31 = xp3[1], q32 = xp3[2];
                a0 += di0 * q00.x; a1 += di0 * q00.y;
                a2 += di0 * q01.x; a3 += di0 * q01.y;
                a4 += di0 * q02.x; a5 += di0 * q02.y;
                a0 += di1 * q10.x; a1 += di1 * q10.y;
                a2 += di1 * q11.x; a3 += di1 * q11.y;
                a4 += di1 * q12.x; a5 += di1 * q12.y;
                a0 += di2 * q20.x; a1 += di2 * q20.y;
                a2 += di2 * q21.x; a3 += di2 * q21.y;
                a4 += di2 * q22.x; a5 += di2 * q22.y;
                a0 += di3 * q30.x; a1 += di3 * q30.y;
                a2 += di3 * q31.x; a3 += di3 * q31.y;
                a4 += di3 * q32.x; a5 += di3 * q32.y;
            }
            for (; j < ne; j++) {
                int s = eidx[j * N_NODES + n];
                float di = rsqrtf(1.0f + (float)cnt[s]);
                const float2* xp = (const float2*)(x + (size_t)s * 12 + grp * 6);
                float2 p0 = xp[0], p1 = xp[1], p2 = xp[2];
                a0 += di * p0.x; a1 += di * p0.y;
                a2 += di * p1.x; a3 += di * p1.y;
                a4 += di * p2.x; a5 += di * p2.y;
            }
            float* ap = &aL[th][grp * 6];
            ap[0] = a0; ap[1] = a1; ap[2] = a2; ap[3] = a3; ap[4] = a4; ap[5] = a5;
        }
    }
    __syncthreads();

    // ---- GCN finalize: u = dinv*a + dinv^2*x ; g = u gw^T + gb
    if (tid < 120) {
        size_t n = (size_t)b0 * TT + tid;
        float di = rsqrtf(1.0f + (float)cnt[n]);
        float d2 = di * di;
        const float4* xp = (const float4*)(x + n * 12);
        float u[12];
        #pragma unroll
        for (int q = 0; q < 3; q++) {
            float4 xv = xp[q];
            u[q*4+0] = di * aL[tid][q*4+0] + d2 * xv.x;
            u[q*4+1] = di * aL[tid][q*4+1] + d2 * xv.y;
            u[q*4+2] = di * aL[tid][q*4+2] + d2 * xv.z;
            u[q*4+3] = di * aL[tid][q*4+3] + d2 * xv.w;
        }
        #pragma unroll
        for (int c = 0; c < 12; c++) {
            float acc = gbl[c];
            #pragma unroll
            for (int j = 0; j < 12; j++) acc += u[j] * gwl[c * 12 + j];
            x0[tid * 12 + c] = acc;
        }
    }
    __syncthreads();

    // ---- conv 12->128 + down, per-thread over t
    int oc = tid & 127, half = tid >> 7;
    float cb = cbl[oc], db = dbl[oc];
    for (int bi = 0; bi < 2; bi++) {
        int bl = bi * 2 + half;
        const float* xb = x0 + bl * (TT * 12);
        float conv[TT], res[TT];
        #pragma unroll
        for (int t = 0; t < TT; t++) { conv[t] = 0.f; res[t] = 0.f; }
        #pragma unroll
        for (int ic = 0; ic < 12; ic++) {
            float w0v = wl[(ic * 3 + 0) * 128 + oc];
            float w1v = wl[(ic * 3 + 1) * 128 + oc];
            float w2v = wl[(ic * 3 + 2) * 128 + oc];
            float dv  = dl[ic * 128 + oc];
            #pragma unroll
            for (int t = 0; t < TT; t++) {
                float xv = xb[t * 12 + ic];
                conv[t] += w2v * xv;
                if (t + 1 < TT) conv[t + 1] += w1v * xv;
                if (t + 2 < TT) conv[t + 2] += w0v * xv;
                res[t] += dv * xv;
            }
        }
        #pragma unroll
        for (int t = 0; t < TT; t++) {
            float o1 = fmaxf(conv[t] + cb, 0.f);
            st[half][t * 136 + oc] = f2bf(fmaxf(o1 + res[t] + db, 0.f));
        }
        __syncthreads();
        for (int idx = tid; idx < 2 * TT * 16; idx += 256) {
            int h = idx / (TT * 16), rem = idx - h * (TT * 16);
            int row = rem >> 4, seg = rem & 15;
            *(uint4*)(X1b + (size_t)((b0 + bi * 2 + h) * TT + row) * 128 + seg * 8) =
                *(const uint4*)(&st[h][row * 136 + seg * 8]);
        }
        __syncthreads();
    }
}

// -------------------------------------------------- TCN blocks 1+2, MFMA
// r11 state (78.5 us, best measured): round-0 structure + cvtpk write-out
// + bias-folded acc init + hoisted first weight prefetches.  Structural
// equilibrium: register pin (wf[2][16] -> ~240 regs/wave -> 2 waves/SIMD)
// and LDS pin (80 KB -> 2 blocks/CU) both bind; 7 structural escapes
// measured worse (8-wave, swizzle, bx-dbuf, rotation, qq-major split,
// 1-batch/WG, stream rotation).
__global__ __launch_bounds__(256, 2) void k_tcn12(
        const unsigned short* __restrict__ X1b,
        const unsigned short* __restrict__ W1f, const unsigned short* __restrict__ D1f,
        const float* __restrict__ cb1, const float* __restrict__ db1,
        const unsigned short* __restrict__ W2f, const unsigned short* __restrict__ D2f,
        const float* __restrict__ cb2, const float* __restrict__ db2,
        unsigned short* __restrict__ X3b) {
    __shared__ __align__(16) unsigned short X1l[61 * 136];  // rows 0..59 data, 60 = zeros
    __shared__ __align__(16) unsigned short X2l[61 * 520];
    const int tid  = threadIdx.x;
    const int lane = tid & 63;
    const int wave = tid >> 6;
    const int tcol = lane & 31;
    const int half = lane >> 5;
    const int b0 = blockIdx.x * 2;

    auto ldw1 = [&](bfrag* dst, int oct, int qc) {
        #pragma unroll
        for (int tap = 0; tap < 3; tap++)
            #pragma unroll
            for (int qq = 0; qq < 4; qq++)
                dst[tap * 4 + qq] =
                    ldf(W1f + (((tap * 8 + qc * 4 + qq) * 16 + oct) << 9) + lane * 8);
        #pragma unroll
        for (int qq = 0; qq < 4; qq++)
            dst[12 + qq] = ldf(D1f + (((qc * 4 + qq) * 16 + oct) << 9) + lane * 8);
    };
    auto ldw2 = [&](bfrag* dst, int oct, int qc) {
        #pragma unroll
        for (int tap = 0; tap < 3; tap++)
            #pragma unroll
            for (int qq = 0; qq < 4; qq++)
                dst[tap * 4 + qq] =
                    ldf(W2f + (((tap * 32 + qc * 4 + qq) * 4 + oct) << 9) + lane * 8);
        #pragma unroll
        for (int qq = 0; qq < 4; qq++)
            dst[12 + qq] = ldf(D2f + (((qc * 4 + qq) * 4 + oct) << 9) + lane * 8);
    };

    // first phase-1 weight prefetch: global->reg only, hoisted above staging
    bfrag wf[2][16];
    ldw1(wf[0], wave, 0);

    for (int idx = tid; idx < 960; idx += 256) {
        int row = idx >> 4, seg = idx & 15;
        *(uint4*)(X1l + row * 136 + seg * 8) =
            *(const uint4*)(X1b + ((size_t)(b0 * 30 + row) << 7) + seg * 8);
    }
    if (tid < 17) *(uint4*)(X1l + 60 * 136 + tid * 8) = make_uint4(0, 0, 0, 0);
    if (tid < 65) *(uint4*)(X2l + 60 * 520 + tid * 8) = make_uint4(0, 0, 0, 0);
    __syncthreads();

    // ---- phase 1: block1 (128->512, k=3 dil=3) + 1x1 down  -> X2l (bf16)
    {
        floatx16 accc[2], accd[2];
        #pragma unroll
        for (int s = 0; s < 8; s++) {
            const int qc = s & 1;
            const int oct = (s >> 1) * 4 + wave;
            if (qc == 0) {
                // bias-folded acc init (channel ocb+j lives at acc[gi*4+j])
                #pragma unroll
                for (int gi = 0; gi < 4; gi++) {
                    int ocb = oct * 32 + half * 4 + gi * 8;
                    float4 cbv = *(const float4*)(cb1 + ocb);
                    float4 dbv = *(const float4*)(db1 + ocb);
                    accc[0][gi*4+0] = cbv.x; accc[0][gi*4+1] = cbv.y;
                    accc[0][gi*4+2] = cbv.z; accc[0][gi*4+3] = cbv.w;
                    accd[0][gi*4+0] = dbv.x; accd[0][gi*4+1] = dbv.y;
                    accd[0][gi*4+2] = dbv.z; accd[0][gi*4+3] = dbv.w;
                    accc[1][gi*4+0] = cbv.x; accc[1][gi*4+1] = cbv.y;
                    accc[1][gi*4+2] = cbv.z; accc[1][gi*4+3] = cbv.w;
                    accd[1][gi*4+0] = dbv.x; accd[1][gi*4+1] = dbv.y;
                    accd[1][gi*4+2] = dbv.z; accd[1][gi*4+3] = dbv.w;
                }
            }
            if (s < 7)
                ldw1(wf[(s + 1) & 1], ((s + 1) >> 1) * 4 + wave, (s + 1) & 1);
            #pragma unroll
            for (int bl = 0; bl < 2; bl++) {
                bfrag bx[3][4];
                #pragma unroll
                for (int si = 0; si < 3; si++) {
                    int trow = tcol - si * 3;
                    const unsigned short* rp = ((unsigned)trow < 30u)
                        ? (X1l + (bl * 30 + trow) * 136) : (X1l + 60 * 136);
                    #pragma unroll
                    for (int qq = 0; qq < 4; qq++)
                        bx[si][qq] = ldf(rp + (qc * 4 + qq) * 16 + half * 8);
                }
                #pragma unroll
                for (int qq = 0; qq < 4; qq++) {
                    accc[bl] = MFMA(wf[s & 1][8 + qq],  bx[0][qq], accc[bl]);
                    accc[bl] = MFMA(wf[s & 1][4 + qq],  bx[1][qq], accc[bl]);
                    accc[bl] = MFMA(wf[s & 1][qq],      bx[2][qq], accc[bl]);
                    accd[bl] = MFMA(wf[s & 1][12 + qq], bx[0][qq], accd[bl]);
                }
            }
            if (qc == 1 && tcol < 30) {
                #pragma unroll
                for (int bl = 0; bl < 2; bl++) {
                    unsigned short* wp = X2l + (bl * 30 + tcol) * 520 + oct * 32 + half * 4;
                    #pragma unroll
                    for (int gi = 0; gi < 4; gi++) {
                        float v0 = fmaxf(fmaxf(accc[bl][gi*4+0], 0.f) + accd[bl][gi*4+0], 0.f);
                        float v1 = fmaxf(fmaxf(accc[bl][gi*4+1], 0.f) + accd[bl][gi*4+1], 0.f);
                        float v2 = fmaxf(fmaxf(accc[bl][gi*4+2], 0.f) + accd[bl][gi*4+2], 0.f);
                        float v3 = fmaxf(fmaxf(accc[bl][gi*4+3], 0.f) + accd[bl][gi*4+3], 0.f);
                        *(uint2*)(wp + gi * 8) = make_uint2(cvtpk(v0, v1), cvtpk(v2, v3));
                    }
                }
            }
        }
    }
    // phase-2 first weight prefetch: issue before the barrier (global->reg)
    bfrag wf2[2][16];
    ldw2(wf2[0], wave, 0);
    __syncthreads();

    // ---- phase 2: block2 (512->128, k=3 dil=9) + 1x1 down -> staged X3
    {
        const int oct = wave;
        floatx16 accc[2], accd[2];
        #pragma unroll
        for (int gi = 0; gi < 4; gi++) {
            int ocb = oct * 32 + half * 4 + gi * 8;
            float4 cbv = *(const float4*)(cb2 + ocb);
            float4 dbv = *(const float4*)(db2 + ocb);
            accc[0][gi*4+0] = cbv.x; accc[0][gi*4+1] = cbv.y;
            accc[0][gi*4+2] = cbv.z; accc[0][gi*4+3] = cbv.w;
            accd[0][gi*4+0] = dbv.x; accd[0][gi*4+1] = dbv.y;
            accd[0][gi*4+2] = dbv.z; accd[0][gi*4+3] = dbv.w;
            accc[1][gi*4+0] = cbv.x; accc[1][gi*4+1] = cbv.y;
            accc[1][gi*4+2] = cbv.z; accc[1][gi*4+3] = cbv.w;
            accd[1][gi*4+0] = dbv.x; accd[1][gi*4+1] = dbv.y;
            accd[1][gi*4+2] = dbv.z; accd[1][gi*4+3] = dbv.w;
        }
        #pragma unroll
        for (int qc = 0; qc < 8; qc++) {
            if (qc < 7) ldw2(wf2[(qc + 1) & 1], oct, qc + 1);
            #pragma unroll
            for (int bl = 0; bl < 2; bl++) {
                bfrag bx[3][4];
                #pragma unroll
                for (int si = 0; si < 3; si++) {
                    int trow = tcol - si * 9;
                    const unsigned short* rp = ((unsigned)trow < 30u)
                        ? (X2l + (bl * 30 + trow) * 520) : (X2l + 60 * 520);
                    #pragma unroll
                    for (int qq = 0; qq < 4; qq++)
                        bx[si][qq] = ldf(rp + (qc * 4 + qq) * 16 + half * 8);
                }
                #pragma unroll
                for (int qq = 0; qq < 4; qq++) {
                    accc[bl] = MFMA(wf2[qc & 1][8 + qq],  bx[0][qq], accc[bl]);
                    accc[bl] = MFMA(wf2[qc & 1][4 + qq],  bx[1][qq], accc[bl]);
                    accc[bl] = MFMA(wf2[qc & 1][qq],      bx[2][qq], accc[bl]);
                    accd[bl] = MFMA(wf2[qc & 1][12 + qq], bx[0][qq], accd[bl]);
                }
            }
        }
        if (tcol < 30) {   // stage into X1l area (free after phase 1)
            #pragma unroll
            for (int bl = 0; bl < 2; bl++) {
                unsigned short* wp = X1l + (bl * 30 + tcol) * 136 + oct * 32 + half * 4;
                #pragma unroll
                for (int gi = 0; gi < 4; gi++) {
                    float v0 = fmaxf(fmaxf(accc[bl][gi*4+0], 0.f) + accd[bl][gi*4+0], 0.f);
                    float v1 = fmaxf(fmaxf(accc[bl][gi*4+1], 0.f) + accd[bl][gi*4+1], 0.f);
                    float v2 = fmaxf(fmaxf(accc[bl][gi*4+2], 0.f) + accd[bl][gi*4+2], 0.f);
                    float v3 = fmaxf(fmaxf(accc[bl][gi*4+3], 0.f) + accd[bl][gi*4+3], 0.f);
                    *(uint2*)(wp + gi * 8) = make_uint2(cvtpk(v0, v1), cvtpk(v2, v3));
                }
            }
        }
    }
    __syncthreads();
    // coalesced flush: 60 rows x 256 B contiguous
    for (int idx = tid; idx < 960; idx += 256) {
        int row = idx >> 4, seg = idx & 15;
        *(uint4*)(X3b + ((size_t)(b0 * 30 + row) << 7) + seg * 8) =
            *(const uint4*)(X1l + row * 136 + seg * 8);
    }
}

// ------------------------------------------------------------- FC (MFMA)
// r10/r11 version restored (grid 256, 128 batches/WG).  r12's grid-512
// split regressed +8.5 us: the fully-unrolled 15-iter loop already gives
// the single wave ample ILP (compiler hoists all 45 weight loads), and the
// split added 2x weight traffic + 2 idle waves + double staging.
__global__ __launch_bounds__(256) void k_fc_mfma(
        const unsigned short* __restrict__ X3b,
        const unsigned short* __restrict__ FCWf,
        unsigned short* __restrict__ P) {
    __shared__ __align__(16) unsigned short xt[128 * 248];   // 240 used + 8 pad
    const int tid  = threadIdx.x;
    const int lane = tid & 63;
    const int wave = tid >> 6;
    const int half = lane >> 5;
    const int bg = blockIdx.x & 15;
    const int kc = blockIdx.x >> 4;

    for (int idx = tid; idx < 128 * 32; idx += 256) {
        int row = idx >> 5, seg = idx & 31;
        if (seg < 30)
            *(uint4*)(xt + row * 248 + seg * 8) =
                *(const uint4*)(X3b + (size_t)(bg * 128 + row) * FCK + kc * 240 + seg * 8);
    }
    __syncthreads();

    const int bl = wave * 32 + (lane & 31);
    floatx16 acc[3];
    acc[0] = 0; acc[1] = 0; acc[2] = 0;
    #pragma unroll
    for (int ql = 0; ql < 15; ql++) {
        int q = kc * 15 + ql;
        bfrag bx = ldf(xt + bl * 248 + ql * 16 + half * 8);
        #pragma unroll
        for (int oct = 0; oct < 3; oct++) {
            bfrag af = ldf(FCWf + ((q * 3 + oct) << 9) + lane * 8);
            acc[oct] = MFMA(af, bx, acc[oct]);
        }
    }
    unsigned short* base = P + (size_t)kc * 96 * BATCH;
    const int b = bg * 128 + bl;
    #pragma unroll
    for (int oct = 0; oct < 3; oct++)
        #pragma unroll
        for (int j = 0; j < 16; j++) {
            int o = oct * 32 + half * 4 + (j >> 2) * 8 + (j & 3);
            base[(size_t)o * BATCH + b] = f2bf(acc[oct][j]);
        }
}

__global__ __launch_bounds__(256) void k_fc_reduce(
        const unsigned short* __restrict__ P, const float* __restrict__ fcb,
        float* __restrict__ out) {
    int j = blockIdx.x * blockDim.x + threadIdx.x;   // j = o*2048 + b, o<72
    int o = j >> 11, b = j & 2047;
    float acc = fcb[o];
    #pragma unroll
    for (int kc = 0; kc < 16; kc++) {
        unsigned u = P[((size_t)kc * 96 + o) * BATCH + b];
        acc += __uint_as_float(u << 16);
    }
    out[b * 72 + o] = acc;
}

// ---------------------------------------------------------------- launch

extern "C" void kernel_launch(void* const* d_in, const int* in_sizes, int n_in,
                              void* d_out, int out_size, void* d_ws, size_t ws_size,
                              hipStream_t stream) {
    const float* x   = (const float*)d_in[0];
    const int*   e32 = (const int*)  d_in[1];
    const float* gw  = (const float*)d_in[2];
    const float* gb  = (const float*)d_in[3];
    const float* cw0 = (const float*)d_in[4];
    const float* cb0 = (const float*)d_in[5];
    const float* dw0 = (const float*)d_in[6];
    const float* db0 = (const float*)d_in[7];
    const float* cw1 = (const float*)d_in[8];
    const float* cb1 = (const float*)d_in[9];
    const float* dw1 = (const float*)d_in[10];
    const float* db1 = (const float*)d_in[11];
    const float* cw2 = (const float*)d_in[12];
    const float* cb2 = (const float*)d_in[13];
    const float* dw2 = (const float*)d_in[14];
    const float* db2 = (const float*)d_in[15];
    const float* fcw = (const float*)d_in[16];
    const float* fcb = (const float*)d_in[17];

    char* w = (char*)d_ws;
    auto alloc = [&](size_t bytes) {
        char* p = w;
        w += (bytes + 255) & ~(size_t)255;
        return p;
    };
    int*            cnt  = (int*)           alloc(N_NODES * 4);
    unsigned short* eidx = (unsigned short*)alloc((size_t)N_NODES * MAXDEG * 2);
    float* w0T  = (float*)alloc(36 * 128 * 4);
    float* d0T  = (float*)alloc(12 * 128 * 4);
    unsigned short* W1f  = (unsigned short*)alloc(196608 * 2);
    unsigned short* D1f  = (unsigned short*)alloc(65536 * 2);
    unsigned short* W2f  = (unsigned short*)alloc(196608 * 2);
    unsigned short* D2f  = (unsigned short*)alloc(65536 * 2);
    unsigned short* FCWf = (unsigned short*)alloc(368640 * 2);
    unsigned short* X1b  = (unsigned short*)alloc((size_t)BATCH * TT * C1 * 2);
    unsigned short* X3b  = (unsigned short*)alloc((size_t)BATCH * TT * C3 * 2);
    unsigned short* P    = (unsigned short*)alloc((size_t)16 * 96 * BATCH * 2);

    hipMemsetAsync(cnt, 0, N_NODES * 4, stream);
    k_edges_repack<<<1920 + 3488, 256, 0, stream>>>(
        e32, cnt, eidx, cw0, dw0, cw1, dw1, cw2, dw2, fcw,
        w0T, d0T, W1f, D1f, W2f, D2f, FCWf);
    k_block0<<<BATCH / 4, 256, 0, stream>>>(x, cnt, eidx, gw, gb,
                                            w0T, d0T, cb0, db0, X1b);
    k_tcn12<<<BATCH / 2, 256, 0, stream>>>(X1b, W1f, D1f, cb1, db1,
                                           W2f, D2f, cb2, db2, X3b);
    k_fc_mfma<<<256, 256, 0, stream>>>(X3b, FCWf, P);
    k_fc_reduce<<<72 * BATCH / 256, 256, 0, stream>>>(P, fcb, (float*)d_out);
}

// Round 14
// 144.253 us; speedup vs baseline: 1.1056x; 1.0484x over previous
//
#include <hip/hip_runtime.h>
#include <hip/hip_bf16.h>

#define N_NODES 61440
#define NEDGE   491520
#define BATCH   2048
#define TT      30
#define C1      128
#define C2      512
#define C3      128
#define FCK     3840   // 128*30
#define MAXDEG  40     // Poisson(8) tail: P(deg>40) ~ 1e-11

typedef float floatx16 __attribute__((ext_vector_type(16)));
typedef __bf16 bfrag   __attribute__((ext_vector_type(8)));

static __device__ __forceinline__ unsigned short f2bf(float f) {
    unsigned u = __float_as_uint(f);
    u = u + 0x7fffu + ((u >> 16) & 1u);
    return (unsigned short)(u >> 16);
}
// packed f32x2 -> bf16x2 (RNE, bit-identical to f2bf pair)
static __device__ __forceinline__ unsigned cvtpk(float lo, float hi) {
    unsigned r;
    asm("v_cvt_pk_bf16_f32 %0, %1, %2" : "=v"(r) : "v"(lo), "v"(hi));
    return r;
}
static __device__ __forceinline__ bfrag ldf(const void* p) { return *(const bfrag*)p; }
#define MFMA(a, b, c) __builtin_amdgcn_mfma_f32_32x32x16_bf16(a, b, c, 0, 0, 0)

// ------------------------------------------- edges + weight repack (merged)
__global__ void k_edges_repack(
        const int* __restrict__ e32, int* __restrict__ cnt,
        unsigned short* __restrict__ eidx,
        const float* __restrict__ cw0, const float* __restrict__ dw0,
        const float* __restrict__ cw1, const float* __restrict__ dw1,
        const float* __restrict__ cw2, const float* __restrict__ dw2,
        const float* __restrict__ fcw,
        float* __restrict__ w0T, float* __restrict__ d0T,
        unsigned short* __restrict__ W1f, unsigned short* __restrict__ D1f,
        unsigned short* __restrict__ W2f, unsigned short* __restrict__ D2f,
        unsigned short* __restrict__ FCWf) {
    if (blockIdx.x < 1920) {
        int i = blockIdx.x * 256 + threadIdx.x;
        bool is64 = (e32[1] == 0) & (e32[3] == 0) & (e32[5] == 0) & (e32[7] == 0);
        int s, d;
        if (is64) { s = e32[2 * i]; d = e32[2 * (NEDGE + i)]; }
        else      { s = e32[i];     d = e32[NEDGE + i]; }
        int slot = atomicAdd(&cnt[d], 1);
        if (slot < MAXDEG) eidx[slot * N_NODES + d] = (unsigned short)s;
        return;
    }
    int i = (blockIdx.x - 1920) * 256 + threadIdx.x;
    if (i < 36 * 128) { int oc = i & 127, r = i >> 7; w0T[i] = cw0[oc * 36 + r]; }
    if (i < 12 * 128) { int oc = i & 127, ic = i >> 7; d0T[i] = dw0[oc * 12 + ic]; }
    if (i < 196608) {                       // W1f
        int pos = i & 511, f = i >> 9;
        int lane = pos >> 3, e = pos & 7;
        int oct = f & 15, q = (f >> 4) & 7, tap = f >> 7;
        int oc = oct * 32 + (lane & 31), ic = q * 16 + (lane >> 5) * 8 + e;
        W1f[i] = f2bf(cw1[(oc * 128 + ic) * 3 + tap]);
    } else if (i < 262144) {                // D1f
        int j = i - 196608;
        int pos = j & 511, f = j >> 9;
        int lane = pos >> 3, e = pos & 7;
        int oct = f & 15, q = f >> 4;
        int oc = oct * 32 + (lane & 31), ic = q * 16 + (lane >> 5) * 8 + e;
        D1f[j] = f2bf(dw1[oc * 128 + ic]);
    } else if (i < 458752) {                // W2f
        int j = i - 262144;
        int pos = j & 511, f = j >> 9;
        int lane = pos >> 3, e = pos & 7;
        int oct = f & 3, q = (f >> 2) & 31, tap = f >> 7;
        int oc = oct * 32 + (lane & 31), ic = q * 16 + (lane >> 5) * 8 + e;
        W2f[j] = f2bf(cw2[(oc * 512 + ic) * 3 + tap]);
    } else if (i < 524288) {                // D2f
        int j = i - 458752;
        int pos = j & 511, f = j >> 9;
        int lane = pos >> 3, e = pos & 7;
        int oct = f & 3, q = f >> 2;
        int oc = oct * 32 + (lane & 31), ic = q * 16 + (lane >> 5) * 8 + e;
        D2f[j] = f2bf(dw2[oc * 512 + ic]);
    } else if (i < 892928) {                // FCWf (240*3 frags)
        int j = i - 524288;
        int pos = j & 511, f = j >> 9;
        int lane = pos >> 3, e = pos & 7;
        int oct = f % 3, q = f / 3;
        int o = oct * 32 + (lane & 31);
        int k = q * 16 + (lane >> 5) * 8 + e;
        float v = (o < 72) ? fcw[o * 3840 + (k & 127) * 30 + (k >> 7)] : 0.f;
        FCWf[j] = f2bf(v);
    }
}

// ------------------------------- TCN blocks 0+1+2, fused (GCN gather + MFMA)
// Round-14: k_block0 FUSED into k_tcn12 as phase 0.  Mechanism: block0 was
// a standalone latency-bound kernel (serial gather chains); fused, its
// exposed L2 latency overlaps the OTHER resident block's MFMA phases
// (2 blocks/CU -> inter-block phase diversity), X1b 15.7 MB write+read
// vanishes, one launch vanishes.  Phase-0 LDS scratch (wl/dl/biases/aL/x0,
// ~32 KB) aliases into X2l (dead until phase 1).  Phase-0 regs (~100) and
// phase-1 regs (~240) are sequential -> no new spill pressure; wf[0]
// prefetch issued only at end of phase 0.  Numerics bit-exact.
__global__ __launch_bounds__(256, 2) void k_tcn012(
        const float* __restrict__ x, const int* __restrict__ cnt,
        const unsigned short* __restrict__ eidx,
        const float* __restrict__ gw, const float* __restrict__ gb,
        const float* __restrict__ w0T, const float* __restrict__ d0T,
        const float* __restrict__ cb0, const float* __restrict__ db0,
        const unsigned short* __restrict__ W1f, const unsigned short* __restrict__ D1f,
        const float* __restrict__ cb1, const float* __restrict__ db1,
        const unsigned short* __restrict__ W2f, const unsigned short* __restrict__ D2f,
        const float* __restrict__ cb2, const float* __restrict__ db2,
        unsigned short* __restrict__ X3b) {
    __shared__ __align__(16) unsigned short X1l[61 * 136];  // rows 0..59 data, 60 = zeros
    __shared__ __align__(16) unsigned short X2l[61 * 520];
    const int tid  = threadIdx.x;
    const int lane = tid & 63;
    const int wave = tid >> 6;
    const int tcol = lane & 31;
    const int half = lane >> 5;
    const int b0 = blockIdx.x * 2;

    // ---- phase 0 scratch aliased into X2l (first ~32 KB; X2l data region
    // is written only in phase 1, after the phase-0 barrier)
    float* wl  = (float*)X2l;           // 36*128
    float* dl  = wl + 36 * 128;         // 12*128
    float* cbl = dl + 12 * 128;         // 128
    float* dbl = cbl + 128;             // 128
    float* gwl = dbl + 128;             // 144
    float* gbl = gwl + 144;             // 12
    float* aL  = gbl + 12;              // 60*12
    float* x0  = aL + 720;              // 2*30*12

    for (int i = tid; i < 36 * 128; i += 256) wl[i] = w0T[i];
    for (int i = tid; i < 12 * 128; i += 256) dl[i] = d0T[i];
    if (tid < 128) { cbl[tid] = cb0[tid]; dbl[tid] = db0[tid]; }
    if (tid < 144) gwl[tid] = gw[tid];
    if (tid >= 144 && tid < 156) gbl[tid - 144] = gb[tid - 144];

    // ---- phase 0a: gather (nodes b0*30 .. b0*30+59), 6 ch per thread half
    {
        int th = tid & 127;
        int grp = tid >> 7;
        if (th < 60) {
            size_t n = (size_t)b0 * TT + th;
            int ne = cnt[n]; if (ne > MAXDEG) ne = MAXDEG;
            float a0 = 0.f, a1 = 0.f, a2 = 0.f, a3 = 0.f, a4 = 0.f, a5 = 0.f;
            int j = 0;
            for (; j + 4 <= ne; j += 4) {
                int s0 = eidx[(j + 0) * N_NODES + n];
                int s1 = eidx[(j + 1) * N_NODES + n];
                int s2 = eidx[(j + 2) * N_NODES + n];
                int s3 = eidx[(j + 3) * N_NODES + n];
                float di0 = rsqrtf(1.0f + (float)cnt[s0]);
                float di1 = rsqrtf(1.0f + (float)cnt[s1]);
                float di2 = rsqrtf(1.0f + (float)cnt[s2]);
                float di3 = rsqrtf(1.0f + (float)cnt[s3]);
                const float2* xp0 = (const float2*)(x + (size_t)s0 * 12 + grp * 6);
                const float2* xp1 = (const float2*)(x + (size_t)s1 * 12 + grp * 6);
                const float2* xp2 = (const float2*)(x + (size_t)s2 * 12 + grp * 6);
                const float2* xp3 = (const float2*)(x + (size_t)s3 * 12 + grp * 6);
                float2 q00 = xp0[0], q01 = xp0[1], q02 = xp0[2];
                float2 q10 = xp1[0], q11 = xp1[1], q12 = xp1[2];
                float2 q20 = xp2[0], q21 = xp2[1], q22 = xp2[2];
                float2 q30 = xp3[0], q31 = xp3[1], q32 = xp3[2];
                a0 += di0 * q00.x; a1 += di0 * q00.y;
                a2 += di0 * q01.x; a3 += di0 * q01.y;
                a4 += di0 * q02.x; a5 += di0 * q02.y;
                a0 += di1 * q10.x; a1 += di1 * q10.y;
                a2 += di1 * q11.x; a3 += di1 * q11.y;
                a4 += di1 * q12.x; a5 += di1 * q12.y;
                a0 += di2 * q20.x; a1 += di2 * q20.y;
                a2 += di2 * q21.x; a3 += di2 * q21.y;
                a4 += di2 * q22.x; a5 += di2 * q22.y;
                a0 += di3 * q30.x; a1 += di3 * q30.y;
                a2 += di3 * q31.x; a3 += di3 * q31.y;
                a4 += di3 * q32.x; a5 += di3 * q32.y;
            }
            for (; j < ne; j++) {
                int s = eidx[j * N_NODES + n];
                float di = rsqrtf(1.0f + (float)cnt[s]);
                const float2* xp = (const float2*)(x + (size_t)s * 12 + grp * 6);
                float2 p0 = xp[0], p1 = xp[1], p2 = xp[2];
                a0 += di * p0.x; a1 += di * p0.y;
                a2 += di * p1.x; a3 += di * p1.y;
                a4 += di * p2.x; a5 += di * p2.y;
            }
            float* ap = aL + th * 12 + grp * 6;
            ap[0] = a0; ap[1] = a1; ap[2] = a2; ap[3] = a3; ap[4] = a4; ap[5] = a5;
        }
    }
    __syncthreads();

    // ---- phase 0b: GCN finalize: u = dinv*a + dinv^2*x ; g = u gw^T + gb
    if (tid < 60) {
        size_t n = (size_t)b0 * TT + tid;
        float di = rsqrtf(1.0f + (float)cnt[n]);
        float d2 = di * di;
        const float4* xp = (const float4*)(x + n * 12);
        float u[12];
        #pragma unroll
        for (int q = 0; q < 3; q++) {
            float4 xv = xp[q];
            u[q*4+0] = di * aL[tid * 12 + q*4+0] + d2 * xv.x;
            u[q*4+1] = di * aL[tid * 12 + q*4+1] + d2 * xv.y;
            u[q*4+2] = di * aL[tid * 12 + q*4+2] + d2 * xv.z;
            u[q*4+3] = di * aL[tid * 12 + q*4+3] + d2 * xv.w;
        }
        #pragma unroll
        for (int c = 0; c < 12; c++) {
            float acc = gbl[c];
            #pragma unroll
            for (int j = 0; j < 12; j++) acc += u[j] * gwl[c * 12 + j];
            x0[tid * 12 + c] = acc;
        }
    }
    __syncthreads();

    // ---- phase 0c: conv 12->128 + down, straight into X1l
    {
        int oc = tid & 127, bl = tid >> 7;
        float cb = cbl[oc], db = dbl[oc];
        const float* xb = x0 + bl * (TT * 12);
        float conv[TT], res[TT];
        #pragma unroll
        for (int t = 0; t < TT; t++) { conv[t] = 0.f; res[t] = 0.f; }
        #pragma unroll
        for (int ic = 0; ic < 12; ic++) {
            float w0v = wl[(ic * 3 + 0) * 128 + oc];
            float w1v = wl[(ic * 3 + 1) * 128 + oc];
            float w2v = wl[(ic * 3 + 2) * 128 + oc];
            float dv  = dl[ic * 128 + oc];
            #pragma unroll
            for (int t = 0; t < TT; t++) {
                float xv = xb[t * 12 + ic];
                conv[t] += w2v * xv;
                if (t + 1 < TT) conv[t + 1] += w1v * xv;
                if (t + 2 < TT) conv[t + 2] += w0v * xv;
                res[t] += dv * xv;
            }
        }
        #pragma unroll
        for (int t = 0; t < TT; t++) {
            float o1 = fmaxf(conv[t] + cb, 0.f);
            X1l[(bl * 30 + t) * 136 + oc] = f2bf(fmaxf(o1 + res[t] + db, 0.f));
        }
    }
    if (tid < 17) *(uint4*)(X1l + 60 * 136 + tid * 8) = make_uint4(0, 0, 0, 0);
    if (tid < 65) *(uint4*)(X2l + 60 * 520 + tid * 8) = make_uint4(0, 0, 0, 0);

    auto ldw1 = [&](bfrag* dst, int oct, int qc) {
        #pragma unroll
        for (int tap = 0; tap < 3; tap++)
            #pragma unroll
            for (int qq = 0; qq < 4; qq++)
                dst[tap * 4 + qq] =
                    ldf(W1f + (((tap * 8 + qc * 4 + qq) * 16 + oct) << 9) + lane * 8);
        #pragma unroll
        for (int qq = 0; qq < 4; qq++)
            dst[12 + qq] = ldf(D1f + (((qc * 4 + qq) * 16 + oct) << 9) + lane * 8);
    };
    auto ldw2 = [&](bfrag* dst, int oct, int qc) {
        #pragma unroll
        for (int tap = 0; tap < 3; tap++)
            #pragma unroll
            for (int qq = 0; qq < 4; qq++)
                dst[tap * 4 + qq] =
                    ldf(W2f + (((tap * 32 + qc * 4 + qq) * 4 + oct) << 9) + lane * 8);
        #pragma unroll
        for (int qq = 0; qq < 4; qq++)
            dst[12 + qq] = ldf(D2f + (((qc * 4 + qq) * 4 + oct) << 9) + lane * 8);
    };

    // first phase-1 weight prefetch: issued at end of phase 0 (keeps phase-0
    // register peak low; global latency overlaps the barrier)
    bfrag wf[2][16];
    ldw1(wf[0], wave, 0);
    __syncthreads();

    // ---- phase 1: block1 (128->512, k=3 dil=3) + 1x1 down  -> X2l (bf16)
    {
        floatx16 accc[2], accd[2];
        #pragma unroll
        for (int s = 0; s < 8; s++) {
            const int qc = s & 1;
            const int oct = (s >> 1) * 4 + wave;
            if (qc == 0) {
                // bias-folded acc init (channel ocb+j lives at acc[gi*4+j])
                #pragma unroll
                for (int gi = 0; gi < 4; gi++) {
                    int ocb = oct * 32 + half * 4 + gi * 8;
                    float4 cbv = *(const float4*)(cb1 + ocb);
                    float4 dbv = *(const float4*)(db1 + ocb);
                    accc[0][gi*4+0] = cbv.x; accc[0][gi*4+1] = cbv.y;
                    accc[0][gi*4+2] = cbv.z; accc[0][gi*4+3] = cbv.w;
                    accd[0][gi*4+0] = dbv.x; accd[0][gi*4+1] = dbv.y;
                    accd[0][gi*4+2] = dbv.z; accd[0][gi*4+3] = dbv.w;
                    accc[1][gi*4+0] = cbv.x; accc[1][gi*4+1] = cbv.y;
                    accc[1][gi*4+2] = cbv.z; accc[1][gi*4+3] = cbv.w;
                    accd[1][gi*4+0] = dbv.x; accd[1][gi*4+1] = dbv.y;
                    accd[1][gi*4+2] = dbv.z; accd[1][gi*4+3] = dbv.w;
                }
            }
            if (s < 7)
                ldw1(wf[(s + 1) & 1], ((s + 1) >> 1) * 4 + wave, (s + 1) & 1);
            #pragma unroll
            for (int bl = 0; bl < 2; bl++) {
                bfrag bx[3][4];
                #pragma unroll
                for (int si = 0; si < 3; si++) {
                    int trow = tcol - si * 3;
                    const unsigned short* rp = ((unsigned)trow < 30u)
                        ? (X1l + (bl * 30 + trow) * 136) : (X1l + 60 * 136);
                    #pragma unroll
                    for (int qq = 0; qq < 4; qq++)
                        bx[si][qq] = ldf(rp + (qc * 4 + qq) * 16 + half * 8);
                }
                #pragma unroll
                for (int qq = 0; qq < 4; qq++) {
                    accc[bl] = MFMA(wf[s & 1][8 + qq],  bx[0][qq], accc[bl]);
                    accc[bl] = MFMA(wf[s & 1][4 + qq],  bx[1][qq], accc[bl]);
                    accc[bl] = MFMA(wf[s & 1][qq],      bx[2][qq], accc[bl]);
                    accd[bl] = MFMA(wf[s & 1][12 + qq], bx[0][qq], accd[bl]);
                }
            }
            if (qc == 1 && tcol < 30) {
                #pragma unroll
                for (int bl = 0; bl < 2; bl++) {
                    unsigned short* wp = X2l + (bl * 30 + tcol) * 520 + oct * 32 + half * 4;
                    #pragma unroll
                    for (int gi = 0; gi < 4; gi++) {
                        float v0 = fmaxf(fmaxf(accc[bl][gi*4+0], 0.f) + accd[bl][gi*4+0], 0.f);
                        float v1 = fmaxf(fmaxf(accc[bl][gi*4+1], 0.f) + accd[bl][gi*4+1], 0.f);
                        float v2 = fmaxf(fmaxf(accc[bl][gi*4+2], 0.f) + accd[bl][gi*4+2], 0.f);
                        float v3 = fmaxf(fmaxf(accc[bl][gi*4+3], 0.f) + accd[bl][gi*4+3], 0.f);
                        *(uint2*)(wp + gi * 8) = make_uint2(cvtpk(v0, v1), cvtpk(v2, v3));
                    }
                }
            }
        }
    }
    // phase-2 first weight prefetch: issue before the barrier (global->reg)
    bfrag wf2[2][16];
    ldw2(wf2[0], wave, 0);
    __syncthreads();

    // ---- phase 2: block2 (512->128, k=3 dil=9) + 1x1 down -> staged X3
    {
        const int oct = wave;
        floatx16 accc[2], accd[2];
        #pragma unroll
        for (int gi = 0; gi < 4; gi++) {
            int ocb = oct * 32 + half * 4 + gi * 8;
            float4 cbv = *(const float4*)(cb2 + ocb);
            float4 dbv = *(const float4*)(db2 + ocb);
            accc[0][gi*4+0] = cbv.x; accc[0][gi*4+1] = cbv.y;
            accc[0][gi*4+2] = cbv.z; accc[0][gi*4+3] = cbv.w;
            accd[0][gi*4+0] = dbv.x; accd[0][gi*4+1] = dbv.y;
            accd[0][gi*4+2] = dbv.z; accd[0][gi*4+3] = dbv.w;
            accc[1][gi*4+0] = cbv.x; accc[1][gi*4+1] = cbv.y;
            accc[1][gi*4+2] = cbv.z; accc[1][gi*4+3] = cbv.w;
            accd[1][gi*4+0] = dbv.x; accd[1][gi*4+1] = dbv.y;
            accd[1][gi*4+2] = dbv.z; accd[1][gi*4+3] = dbv.w;
        }
        #pragma unroll
        for (int qc = 0; qc < 8; qc++) {
            if (qc < 7) ldw2(wf2[(qc + 1) & 1], oct, qc + 1);
            #pragma unroll
            for (int bl = 0; bl < 2; bl++) {
                bfrag bx[3][4];
                #pragma unroll
                for (int si = 0; si < 3; si++) {
                    int trow = tcol - si * 9;
                    const unsigned short* rp = ((unsigned)trow < 30u)
                        ? (X2l + (bl * 30 + trow) * 520) : (X2l + 60 * 520);
                    #pragma unroll
                    for (int qq = 0; qq < 4; qq++)
                        bx[si][qq] = ldf(rp + (qc * 4 + qq) * 16 + half * 8);
                }
                #pragma unroll
                for (int qq = 0; qq < 4; qq++) {
                    accc[bl] = MFMA(wf2[qc & 1][8 + qq],  bx[0][qq], accc[bl]);
                    accc[bl] = MFMA(wf2[qc & 1][4 + qq],  bx[1][qq], accc[bl]);
                    accc[bl] = MFMA(wf2[qc & 1][qq],      bx[2][qq], accc[bl]);
                    accd[bl] = MFMA(wf2[qc & 1][12 + qq], bx[0][qq], accd[bl]);
                }
            }
        }
        if (tcol < 30) {   // stage into X1l area (free after phase 1)
            #pragma unroll
            for (int bl = 0; bl < 2; bl++) {
                unsigned short* wp = X1l + (bl * 30 + tcol) * 136 + oct * 32 + half * 4;
                #pragma unroll
                for (int gi = 0; gi < 4; gi++) {
                    float v0 = fmaxf(fmaxf(accc[bl][gi*4+0], 0.f) + accd[bl][gi*4+0], 0.f);
                    float v1 = fmaxf(fmaxf(accc[bl][gi*4+1], 0.f) + accd[bl][gi*4+1], 0.f);
                    float v2 = fmaxf(fmaxf(accc[bl][gi*4+2], 0.f) + accd[bl][gi*4+2], 0.f);
                    float v3 = fmaxf(fmaxf(accc[bl][gi*4+3], 0.f) + accd[bl][gi*4+3], 0.f);
                    *(uint2*)(wp + gi * 8) = make_uint2(cvtpk(v0, v1), cvtpk(v2, v3));
                }
            }
        }
    }
    __syncthreads();
    // coalesced flush: 60 rows x 256 B contiguous
    for (int idx = tid; idx < 960; idx += 256) {
        int row = idx >> 4, seg = idx & 15;
        *(uint4*)(X3b + ((size_t)(b0 * 30 + row) << 7) + seg * 8) =
            *(const uint4*)(X1l + row * 136 + seg * 8);
    }
}

// ------------------------------------------------------------- FC (MFMA)
// Deterministic two-stage scheme (bf16 partials, fixed kc reduction order).
__global__ __launch_bounds__(256) void k_fc_mfma(
        const unsigned short* __restrict__ X3b,
        const unsigned short* __restrict__ FCWf,
        unsigned short* __restrict__ P) {
    __shared__ __align__(16) unsigned short xt[128 * 248];   // 240 used + 8 pad
    const int tid  = threadIdx.x;
    const int lane = tid & 63;
    const int wave = tid >> 6;
    const int half = lane >> 5;
    const int bg = blockIdx.x & 15;
    const int kc = blockIdx.x >> 4;

    for (int idx = tid; idx < 128 * 32; idx += 256) {
        int row = idx >> 5, seg = idx & 31;
        if (seg < 30)
            *(uint4*)(xt + row * 248 + seg * 8) =
                *(const uint4*)(X3b + (size_t)(bg * 128 + row) * FCK + kc * 240 + seg * 8);
    }
    __syncthreads();

    const int bl = wave * 32 + (lane & 31);
    floatx16 acc[3];
    acc[0] = 0; acc[1] = 0; acc[2] = 0;
    #pragma unroll
    for (int ql = 0; ql < 15; ql++) {
        int q = kc * 15 + ql;
        bfrag bx = ldf(xt + bl * 248 + ql * 16 + half * 8);
        #pragma unroll
        for (int oct = 0; oct < 3; oct++) {
            bfrag af = ldf(FCWf + ((q * 3 + oct) << 9) + lane * 8);
            acc[oct] = MFMA(af, bx, acc[oct]);
        }
    }
    unsigned short* base = P + (size_t)kc * 96 * BATCH;
    const int b = bg * 128 + bl;
    #pragma unroll
    for (int oct = 0; oct < 3; oct++)
        #pragma unroll
        for (int j = 0; j < 16; j++) {
            int o = oct * 32 + half * 4 + (j >> 2) * 8 + (j & 3);
            base[(size_t)o * BATCH + b] = f2bf(acc[oct][j]);
        }
}

__global__ __launch_bounds__(256) void k_fc_reduce(
        const unsigned short* __restrict__ P, const float* __restrict__ fcb,
        float* __restrict__ out) {
    int j = blockIdx.x * blockDim.x + threadIdx.x;   // j = o*2048 + b, o<72
    int o = j >> 11, b = j & 2047;
    float acc = fcb[o];
    #pragma unroll
    for (int kc = 0; kc < 16; kc++) {
        unsigned u = P[((size_t)kc * 96 + o) * BATCH + b];
        acc += __uint_as_float(u << 16);
    }
    out[b * 72 + o] = acc;
}

// ---------------------------------------------------------------- launch

extern "C" void kernel_launch(void* const* d_in, const int* in_sizes, int n_in,
                              void* d_out, int out_size, void* d_ws, size_t ws_size,
                              hipStream_t stream) {
    const float* x   = (const float*)d_in[0];
    const int*   e32 = (const int*)  d_in[1];
    const float* gw  = (const float*)d_in[2];
    const float* gb  = (const float*)d_in[3];
    const float* cw0 = (const float*)d_in[4];
    const float* cb0 = (const float*)d_in[5];
    const float* dw0 = (const float*)d_in[6];
    const float* db0 = (const float*)d_in[7];
    const float* cw1 = (const float*)d_in[8];
    const float* cb1 = (const float*)d_in[9];
    const float* dw1 = (const float*)d_in[10];
    const float* db1 = (const float*)d_in[11];
    const float* cw2 = (const float*)d_in[12];
    const float* cb2 = (const float*)d_in[13];
    const float* dw2 = (const float*)d_in[14];
    const float* db2 = (const float*)d_in[15];
    const float* fcw = (const float*)d_in[16];
    const float* fcb = (const float*)d_in[17];

    char* w = (char*)d_ws;
    auto alloc = [&](size_t bytes) {
        char* p = w;
        w += (bytes + 255) & ~(size_t)255;
        return p;
    };
    int*            cnt  = (int*)           alloc(N_NODES * 4);
    unsigned short* eidx = (unsigned short*)alloc((size_t)N_NODES * MAXDEG * 2);
    float* w0T  = (float*)alloc(36 * 128 * 4);
    float* d0T  = (float*)alloc(12 * 128 * 4);
    unsigned short* W1f  = (unsigned short*)alloc(196608 * 2);
    unsigned short* D1f  = (unsigned short*)alloc(65536 * 2);
    unsigned short* W2f  = (unsigned short*)alloc(196608 * 2);
    unsigned short* D2f  = (unsigned short*)alloc(65536 * 2);
    unsigned short* FCWf = (unsigned short*)alloc(368640 * 2);
    unsigned short* X3b  = (unsigned short*)alloc((size_t)BATCH * TT * C3 * 2);
    unsigned short* P    = (unsigned short*)alloc((size_t)16 * 96 * BATCH * 2);

    hipMemsetAsync(cnt, 0, N_NODES * 4, stream);
    k_edges_repack<<<1920 + 3488, 256, 0, stream>>>(
        e32, cnt, eidx, cw0, dw0, cw1, dw1, cw2, dw2, fcw,
        w0T, d0T, W1f, D1f, W2f, D2f, FCWf);
    k_tcn012<<<BATCH / 2, 256, 0, stream>>>(
        x, cnt, eidx, gw, gb, w0T, d0T, cb0, db0,
        W1f, D1f, cb1, db1, W2f, D2f, cb2, db2, X3b);
    k_fc_mfma<<<256, 256, 0, stream>>>(X3b, FCWf, P);
    k_fc_reduce<<<72 * BATCH / 256, 256, 0, stream>>>(P, fcb, (float*)d_out);
}

// Round 15
// 139.239 us; speedup vs baseline: 1.1454x; 1.0360x over previous
//
#include <hip/hip_runtime.h>
#include <hip/hip_bf16.h>

#define N_NODES 61440
#define NEDGE   491520
#define BATCH   2048
#define TT      30
#define C1      128
#define C2      512
#define C3      128
#define FCK     3840   // 128*30
#define MAXDEG  40     // Poisson(8) tail: P(deg>40) ~ 1e-11

typedef float floatx16 __attribute__((ext_vector_type(16)));
typedef __bf16 bfrag   __attribute__((ext_vector_type(8)));

static __device__ __forceinline__ unsigned short f2bf(float f) {
    unsigned u = __float_as_uint(f);
    u = u + 0x7fffu + ((u >> 16) & 1u);
    return (unsigned short)(u >> 16);
}
// packed f32x2 -> bf16x2 (RNE, bit-identical to f2bf pair)
static __device__ __forceinline__ unsigned cvtpk(float lo, float hi) {
    unsigned r;
    asm("v_cvt_pk_bf16_f32 %0, %1, %2" : "=v"(r) : "v"(lo), "v"(hi));
    return r;
}
static __device__ __forceinline__ bfrag ldf(const void* p) { return *(const bfrag*)p; }
#define MFMA(a, b, c) __builtin_amdgcn_mfma_f32_32x32x16_bf16(a, b, c, 0, 0, 0)

// ------------------------------------------- edges + weight repack (merged)
__global__ void k_edges_repack(
        const int* __restrict__ e32, int* __restrict__ cnt,
        unsigned short* __restrict__ eidx,
        const float* __restrict__ cw0, const float* __restrict__ dw0,
        const float* __restrict__ cw1, const float* __restrict__ dw1,
        const float* __restrict__ cw2, const float* __restrict__ dw2,
        const float* __restrict__ fcw,
        float* __restrict__ w0T, float* __restrict__ d0T,
        unsigned short* __restrict__ W1f, unsigned short* __restrict__ D1f,
        unsigned short* __restrict__ W2f, unsigned short* __restrict__ D2f,
        unsigned short* __restrict__ FCWf) {
    if (blockIdx.x < 1920) {
        int i = blockIdx.x * 256 + threadIdx.x;
        bool is64 = (e32[1] == 0) & (e32[3] == 0) & (e32[5] == 0) & (e32[7] == 0);
        int s, d;
        if (is64) { s = e32[2 * i]; d = e32[2 * (NEDGE + i)]; }
        else      { s = e32[i];     d = e32[NEDGE + i]; }
        int slot = atomicAdd(&cnt[d], 1);
        if (slot < MAXDEG) eidx[slot * N_NODES + d] = (unsigned short)s;
        return;
    }
    int i = (blockIdx.x - 1920) * 256 + threadIdx.x;
    if (i < 36 * 128) { int oc = i & 127, r = i >> 7; w0T[i] = cw0[oc * 36 + r]; }
    if (i < 12 * 128) { int oc = i & 127, ic = i >> 7; d0T[i] = dw0[oc * 12 + ic]; }
    if (i < 196608) {                       // W1f
        int pos = i & 511, f = i >> 9;
        int lane = pos >> 3, e = pos & 7;
        int oct = f & 15, q = (f >> 4) & 7, tap = f >> 7;
        int oc = oct * 32 + (lane & 31), ic = q * 16 + (lane >> 5) * 8 + e;
        W1f[i] = f2bf(cw1[(oc * 128 + ic) * 3 + tap]);
    } else if (i < 262144) {                // D1f
        int j = i - 196608;
        int pos = j & 511, f = j >> 9;
        int lane = pos >> 3, e = pos & 7;
        int oct = f & 15, q = f >> 4;
        int oc = oct * 32 + (lane & 31), ic = q * 16 + (lane >> 5) * 8 + e;
        D1f[j] = f2bf(dw1[oc * 128 + ic]);
    } else if (i < 458752) {                // W2f
        int j = i - 262144;
        int pos = j & 511, f = j >> 9;
        int lane = pos >> 3, e = pos & 7;
        int oct = f & 3, q = (f >> 2) & 31, tap = f >> 7;
        int oc = oct * 32 + (lane & 31), ic = q * 16 + (lane >> 5) * 8 + e;
        W2f[j] = f2bf(cw2[(oc * 512 + ic) * 3 + tap]);
    } else if (i < 524288) {                // D2f
        int j = i - 458752;
        int pos = j & 511, f = j >> 9;
        int lane = pos >> 3, e = pos & 7;
        int oct = f & 3, q = f >> 2;
        int oc = oct * 32 + (lane & 31), ic = q * 16 + (lane >> 5) * 8 + e;
        D2f[j] = f2bf(dw2[oc * 512 + ic]);
    } else if (i < 892928) {                // FCWf (240*3 frags)
        int j = i - 524288;
        int pos = j & 511, f = j >> 9;
        int lane = pos >> 3, e = pos & 7;
        int oct = f % 3, q = f / 3;
        int o = oct * 32 + (lane & 31);
        int k = q * 16 + (lane >> 5) * 8 + e;
        float v = (o < 72) ? fcw[o * 3840 + (k & 127) * 30 + (k >> 7)] : 0.f;
        FCWf[j] = f2bf(v);
    }
}

// ------------------------------- TCN blocks 0+1+2, fused (GCN gather + MFMA)
// r14 win (144.3 us): k_block0 fused as phase 0 (X1b 15.7 MB round-trip +
// launch gap eliminated).  Round-15: gather parallelism doubled — 2 threads
// per (node, channel-group), each summing half the neighbor list (240 of
// 256 threads active, chain length halved); partials combined in phase 0b
// (one f32 add reorder, ~1e-7, deterministic).
__global__ __launch_bounds__(256, 2) void k_tcn012(
        const float* __restrict__ x, const int* __restrict__ cnt,
        const unsigned short* __restrict__ eidx,
        const float* __restrict__ gw, const float* __restrict__ gb,
        const float* __restrict__ w0T, const float* __restrict__ d0T,
        const float* __restrict__ cb0, const float* __restrict__ db0,
        const unsigned short* __restrict__ W1f, const unsigned short* __restrict__ D1f,
        const float* __restrict__ cb1, const float* __restrict__ db1,
        const unsigned short* __restrict__ W2f, const unsigned short* __restrict__ D2f,
        const float* __restrict__ cb2, const float* __restrict__ db2,
        unsigned short* __restrict__ X3b) {
    __shared__ __align__(16) unsigned short X1l[61 * 136];  // rows 0..59 data, 60 = zeros
    __shared__ __align__(16) unsigned short X2l[61 * 520];
    const int tid  = threadIdx.x;
    const int lane = tid & 63;
    const int wave = tid >> 6;
    const int tcol = lane & 31;
    const int half = lane >> 5;
    const int b0 = blockIdx.x * 2;

    // ---- phase 0 scratch aliased into X2l (first ~35 KB; X2l data region
    // is written only in phase 1, after the phase-0 barrier)
    float* wl  = (float*)X2l;           // 36*128
    float* dl  = wl + 36 * 128;         // 12*128
    float* cbl = dl + 12 * 128;         // 128
    float* dbl = cbl + 128;             // 128
    float* gwl = dbl + 128;             // 144
    float* gbl = gwl + 144;             // 12
    float* aL  = gbl + 12;              // 60*2*12 (node, part)
    float* x0  = aL + 1440;             // 2*30*12

    for (int i = tid; i < 36 * 128; i += 256) wl[i] = w0T[i];
    for (int i = tid; i < 12 * 128; i += 256) dl[i] = d0T[i];
    if (tid < 128) { cbl[tid] = cb0[tid]; dbl[tid] = db0[tid]; }
    if (tid < 144) gwl[tid] = gw[tid];
    if (tid >= 144 && tid < 156) gbl[tid - 144] = gb[tid - 144];

    // ---- phase 0a: gather, 2 threads/(node,grp): part p sums half the list
    if (tid < 240) {
        int node = tid % 60;
        int rest = tid / 60;            // 0..3
        int part = rest & 1;
        int grp  = rest >> 1;
        size_t n = (size_t)b0 * TT + node;
        int ne = cnt[n]; if (ne > MAXDEG) ne = MAXDEG;
        int j0 = part ? (ne >> 1) : 0;
        int j1 = part ? ne : (ne >> 1);
        float a0 = 0.f, a1 = 0.f, a2 = 0.f, a3 = 0.f, a4 = 0.f, a5 = 0.f;
        int j = j0;
        for (; j + 4 <= j1; j += 4) {
            int s0 = eidx[(j + 0) * N_NODES + n];
            int s1 = eidx[(j + 1) * N_NODES + n];
            int s2 = eidx[(j + 2) * N_NODES + n];
            int s3 = eidx[(j + 3) * N_NODES + n];
            float di0 = rsqrtf(1.0f + (float)cnt[s0]);
            float di1 = rsqrtf(1.0f + (float)cnt[s1]);
            float di2 = rsqrtf(1.0f + (float)cnt[s2]);
            float di3 = rsqrtf(1.0f + (float)cnt[s3]);
            const float2* xp0 = (const float2*)(x + (size_t)s0 * 12 + grp * 6);
            const float2* xp1 = (const float2*)(x + (size_t)s1 * 12 + grp * 6);
            const float2* xp2 = (const float2*)(x + (size_t)s2 * 12 + grp * 6);
            const float2* xp3 = (const float2*)(x + (size_t)s3 * 12 + grp * 6);
            float2 q00 = xp0[0], q01 = xp0[1], q02 = xp0[2];
            float2 q10 = xp1[0], q11 = xp1[1], q12 = xp1[2];
            float2 q20 = xp2[0], q21 = xp2[1], q22 = xp2[2];
            float2 q30 = xp3[0], q31 = xp3[1], q32 = xp3[2];
            a0 += di0 * q00.x; a1 += di0 * q00.y;
            a2 += di0 * q01.x; a3 += di0 * q01.y;
            a4 += di0 * q02.x; a5 += di0 * q02.y;
            a0 += di1 * q10.x; a1 += di1 * q10.y;
            a2 += di1 * q11.x; a3 += di1 * q11.y;
            a4 += di1 * q12.x; a5 += di1 * q12.y;
            a0 += di2 * q20.x; a1 += di2 * q20.y;
            a2 += di2 * q21.x; a3 += di2 * q21.y;
            a4 += di2 * q22.x; a5 += di2 * q22.y;
            a0 += di3 * q30.x; a1 += di3 * q30.y;
            a2 += di3 * q31.x; a3 += di3 * q31.y;
            a4 += di3 * q32.x; a5 += di3 * q32.y;
        }
        for (; j < j1; j++) {
            int s = eidx[j * N_NODES + n];
            float di = rsqrtf(1.0f + (float)cnt[s]);
            const float2* xp = (const float2*)(x + (size_t)s * 12 + grp * 6);
            float2 p0 = xp[0], p1 = xp[1], p2 = xp[2];
            a0 += di * p0.x; a1 += di * p0.y;
            a2 += di * p1.x; a3 += di * p1.y;
            a4 += di * p2.x; a5 += di * p2.y;
        }
        float* ap = aL + (node * 2 + part) * 12 + grp * 6;
        ap[0] = a0; ap[1] = a1; ap[2] = a2; ap[3] = a3; ap[4] = a4; ap[5] = a5;
    }
    __syncthreads();

    // ---- phase 0b: GCN finalize: u = dinv*(p0+p1) + dinv^2*x ; g = u gw^T + gb
    if (tid < 60) {
        size_t n = (size_t)b0 * TT + tid;
        float di = rsqrtf(1.0f + (float)cnt[n]);
        float d2 = di * di;
        const float4* xp = (const float4*)(x + n * 12);
        const float* p0 = aL + (tid * 2 + 0) * 12;
        const float* p1 = aL + (tid * 2 + 1) * 12;
        float u[12];
        #pragma unroll
        for (int q = 0; q < 3; q++) {
            float4 xv = xp[q];
            u[q*4+0] = di * (p0[q*4+0] + p1[q*4+0]) + d2 * xv.x;
            u[q*4+1] = di * (p0[q*4+1] + p1[q*4+1]) + d2 * xv.y;
            u[q*4+2] = di * (p0[q*4+2] + p1[q*4+2]) + d2 * xv.z;
            u[q*4+3] = di * (p0[q*4+3] + p1[q*4+3]) + d2 * xv.w;
        }
        #pragma unroll
        for (int c = 0; c < 12; c++) {
            float acc = gbl[c];
            #pragma unroll
            for (int j = 0; j < 12; j++) acc += u[j] * gwl[c * 12 + j];
            x0[tid * 12 + c] = acc;
        }
    }
    __syncthreads();

    // ---- phase 0c: conv 12->128 + down, straight into X1l
    {
        int oc = tid & 127, bl = tid >> 7;
        float cb = cbl[oc], db = dbl[oc];
        const float* xb = x0 + bl * (TT * 12);
        float conv[TT], res[TT];
        #pragma unroll
        for (int t = 0; t < TT; t++) { conv[t] = 0.f; res[t] = 0.f; }
        #pragma unroll
        for (int ic = 0; ic < 12; ic++) {
            float w0v = wl[(ic * 3 + 0) * 128 + oc];
            float w1v = wl[(ic * 3 + 1) * 128 + oc];
            float w2v = wl[(ic * 3 + 2) * 128 + oc];
            float dv  = dl[ic * 128 + oc];
            #pragma unroll
            for (int t = 0; t < TT; t++) {
                float xv = xb[t * 12 + ic];
                conv[t] += w2v * xv;
                if (t + 1 < TT) conv[t + 1] += w1v * xv;
                if (t + 2 < TT) conv[t + 2] += w0v * xv;
                res[t] += dv * xv;
            }
        }
        #pragma unroll
        for (int t = 0; t < TT; t++) {
            float o1 = fmaxf(conv[t] + cb, 0.f);
            X1l[(bl * 30 + t) * 136 + oc] = f2bf(fmaxf(o1 + res[t] + db, 0.f));
        }
    }
    if (tid < 17) *(uint4*)(X1l + 60 * 136 + tid * 8) = make_uint4(0, 0, 0, 0);
    if (tid < 65) *(uint4*)(X2l + 60 * 520 + tid * 8) = make_uint4(0, 0, 0, 0);

    auto ldw1 = [&](bfrag* dst, int oct, int qc) {
        #pragma unroll
        for (int tap = 0; tap < 3; tap++)
            #pragma unroll
            for (int qq = 0; qq < 4; qq++)
                dst[tap * 4 + qq] =
                    ldf(W1f + (((tap * 8 + qc * 4 + qq) * 16 + oct) << 9) + lane * 8);
        #pragma unroll
        for (int qq = 0; qq < 4; qq++)
            dst[12 + qq] = ldf(D1f + (((qc * 4 + qq) * 16 + oct) << 9) + lane * 8);
    };
    auto ldw2 = [&](bfrag* dst, int oct, int qc) {
        #pragma unroll
        for (int tap = 0; tap < 3; tap++)
            #pragma unroll
            for (int qq = 0; qq < 4; qq++)
                dst[tap * 4 + qq] =
                    ldf(W2f + (((tap * 32 + qc * 4 + qq) * 4 + oct) << 9) + lane * 8);
        #pragma unroll
        for (int qq = 0; qq < 4; qq++)
            dst[12 + qq] = ldf(D2f + (((qc * 4 + qq) * 4 + oct) << 9) + lane * 8);
    };

    // first phase-1 weight prefetch: issued at end of phase 0 (keeps phase-0
    // register peak low; global latency overlaps the barrier)
    bfrag wf[2][16];
    ldw1(wf[0], wave, 0);
    __syncthreads();

    // ---- phase 1: block1 (128->512, k=3 dil=3) + 1x1 down  -> X2l (bf16)
    {
        floatx16 accc[2], accd[2];
        #pragma unroll
        for (int s = 0; s < 8; s++) {
            const int qc = s & 1;
            const int oct = (s >> 1) * 4 + wave;
            if (qc == 0) {
                // bias-folded acc init (channel ocb+j lives at acc[gi*4+j])
                #pragma unroll
                for (int gi = 0; gi < 4; gi++) {
                    int ocb = oct * 32 + half * 4 + gi * 8;
                    float4 cbv = *(const float4*)(cb1 + ocb);
                    float4 dbv = *(const float4*)(db1 + ocb);
                    accc[0][gi*4+0] = cbv.x; accc[0][gi*4+1] = cbv.y;
                    accc[0][gi*4+2] = cbv.z; accc[0][gi*4+3] = cbv.w;
                    accd[0][gi*4+0] = dbv.x; accd[0][gi*4+1] = dbv.y;
                    accd[0][gi*4+2] = dbv.z; accd[0][gi*4+3] = dbv.w;
                    accc[1][gi*4+0] = cbv.x; accc[1][gi*4+1] = cbv.y;
                    accc[1][gi*4+2] = cbv.z; accc[1][gi*4+3] = cbv.w;
                    accd[1][gi*4+0] = dbv.x; accd[1][gi*4+1] = dbv.y;
                    accd[1][gi*4+2] = dbv.z; accd[1][gi*4+3] = dbv.w;
                }
            }
            if (s < 7)
                ldw1(wf[(s + 1) & 1], ((s + 1) >> 1) * 4 + wave, (s + 1) & 1);
            #pragma unroll
            for (int bl = 0; bl < 2; bl++) {
                bfrag bx[3][4];
                #pragma unroll
                for (int si = 0; si < 3; si++) {
                    int trow = tcol - si * 3;
                    const unsigned short* rp = ((unsigned)trow < 30u)
                        ? (X1l + (bl * 30 + trow) * 136) : (X1l + 60 * 136);
                    #pragma unroll
                    for (int qq = 0; qq < 4; qq++)
                        bx[si][qq] = ldf(rp + (qc * 4 + qq) * 16 + half * 8);
                }
                #pragma unroll
                for (int qq = 0; qq < 4; qq++) {
                    accc[bl] = MFMA(wf[s & 1][8 + qq],  bx[0][qq], accc[bl]);
                    accc[bl] = MFMA(wf[s & 1][4 + qq],  bx[1][qq], accc[bl]);
                    accc[bl] = MFMA(wf[s & 1][qq],      bx[2][qq], accc[bl]);
                    accd[bl] = MFMA(wf[s & 1][12 + qq], bx[0][qq], accd[bl]);
                }
            }
            if (qc == 1 && tcol < 30) {
                #pragma unroll
                for (int bl = 0; bl < 2; bl++) {
                    unsigned short* wp = X2l + (bl * 30 + tcol) * 520 + oct * 32 + half * 4;
                    #pragma unroll
                    for (int gi = 0; gi < 4; gi++) {
                        float v0 = fmaxf(fmaxf(accc[bl][gi*4+0], 0.f) + accd[bl][gi*4+0], 0.f);
                        float v1 = fmaxf(fmaxf(accc[bl][gi*4+1], 0.f) + accd[bl][gi*4+1], 0.f);
                        float v2 = fmaxf(fmaxf(accc[bl][gi*4+2], 0.f) + accd[bl][gi*4+2], 0.f);
                        float v3 = fmaxf(fmaxf(accc[bl][gi*4+3], 0.f) + accd[bl][gi*4+3], 0.f);
                        *(uint2*)(wp + gi * 8) = make_uint2(cvtpk(v0, v1), cvtpk(v2, v3));
                    }
                }
            }
        }
    }
    // phase-2 first weight prefetch: issue before the barrier (global->reg)
    bfrag wf2[2][16];
    ldw2(wf2[0], wave, 0);
    __syncthreads();

    // ---- phase 2: block2 (512->128, k=3 dil=9) + 1x1 down -> staged X3
    {
        const int oct = wave;
        floatx16 accc[2], accd[2];
        #pragma unroll
        for (int gi = 0; gi < 4; gi++) {
            int ocb = oct * 32 + half * 4 + gi * 8;
            float4 cbv = *(const float4*)(cb2 + ocb);
            float4 dbv = *(const float4*)(db2 + ocb);
            accc[0][gi*4+0] = cbv.x; accc[0][gi*4+1] = cbv.y;
            accc[0][gi*4+2] = cbv.z; accc[0][gi*4+3] = cbv.w;
            accd[0][gi*4+0] = dbv.x; accd[0][gi*4+1] = dbv.y;
            accd[0][gi*4+2] = dbv.z; accd[0][gi*4+3] = dbv.w;
            accc[1][gi*4+0] = cbv.x; accc[1][gi*4+1] = cbv.y;
            accc[1][gi*4+2] = cbv.z; accc[1][gi*4+3] = cbv.w;
            accd[1][gi*4+0] = dbv.x; accd[1][gi*4+1] = dbv.y;
            accd[1][gi*4+2] = dbv.z; accd[1][gi*4+3] = dbv.w;
        }
        #pragma unroll
        for (int qc = 0; qc < 8; qc++) {
            if (qc < 7) ldw2(wf2[(qc + 1) & 1], oct, qc + 1);
            #pragma unroll
            for (int bl = 0; bl < 2; bl++) {
                bfrag bx[3][4];
                #pragma unroll
                for (int si = 0; si < 3; si++) {
                    int trow = tcol - si * 9;
                    const unsigned short* rp = ((unsigned)trow < 30u)
                        ? (X2l + (bl * 30 + trow) * 520) : (X2l + 60 * 520);
                    #pragma unroll
                    for (int qq = 0; qq < 4; qq++)
                        bx[si][qq] = ldf(rp + (qc * 4 + qq) * 16 + half * 8);
                }
                #pragma unroll
                for (int qq = 0; qq < 4; qq++) {
                    accc[bl] = MFMA(wf2[qc & 1][8 + qq],  bx[0][qq], accc[bl]);
                    accc[bl] = MFMA(wf2[qc & 1][4 + qq],  bx[1][qq], accc[bl]);
                    accc[bl] = MFMA(wf2[qc & 1][qq],      bx[2][qq], accc[bl]);
                    accd[bl] = MFMA(wf2[qc & 1][12 + qq], bx[0][qq], accd[bl]);
                }
            }
        }
        if (tcol < 30) {   // stage into X1l area (free after phase 1)
            #pragma unroll
            for (int bl = 0; bl < 2; bl++) {
                unsigned short* wp = X1l + (bl * 30 + tcol) * 136 + oct * 32 + half * 4;
                #pragma unroll
                for (int gi = 0; gi < 4; gi++) {
                    float v0 = fmaxf(fmaxf(accc[bl][gi*4+0], 0.f) + accd[bl][gi*4+0], 0.f);
                    float v1 = fmaxf(fmaxf(accc[bl][gi*4+1], 0.f) + accd[bl][gi*4+1], 0.f);
                    float v2 = fmaxf(fmaxf(accc[bl][gi*4+2], 0.f) + accd[bl][gi*4+2], 0.f);
                    float v3 = fmaxf(fmaxf(accc[bl][gi*4+3], 0.f) + accd[bl][gi*4+3], 0.f);
                    *(uint2*)(wp + gi * 8) = make_uint2(cvtpk(v0, v1), cvtpk(v2, v3));
                }
            }
        }
    }
    __syncthreads();
    // coalesced flush: 60 rows x 256 B contiguous
    for (int idx = tid; idx < 960; idx += 256) {
        int row = idx >> 4, seg = idx & 15;
        *(uint4*)(X3b + ((size_t)(b0 * 30 + row) << 7) + seg * 8) =
            *(const uint4*)(X1l + row * 136 + seg * 8);
    }
}

// ------------------------------------------------------------- FC (MFMA)
// Deterministic two-stage scheme (bf16 partials, fixed kc reduction order).
__global__ __launch_bounds__(256) void k_fc_mfma(
        const unsigned short* __restrict__ X3b,
        const unsigned short* __restrict__ FCWf,
        unsigned short* __restrict__ P) {
    __shared__ __align__(16) unsigned short xt[128 * 248];   // 240 used + 8 pad
    const int tid  = threadIdx.x;
    const int lane = tid & 63;
    const int wave = tid >> 6;
    const int half = lane >> 5;
    const int bg = blockIdx.x & 15;
    const int kc = blockIdx.x >> 4;

    for (int idx = tid; idx < 128 * 32; idx += 256) {
        int row = idx >> 5, seg = idx & 31;
        if (seg < 30)
            *(uint4*)(xt + row * 248 + seg * 8) =
                *(const uint4*)(X3b + (size_t)(bg * 128 + row) * FCK + kc * 240 + seg * 8);
    }
    __syncthreads();

    const int bl = wave * 32 + (lane & 31);
    floatx16 acc[3];
    acc[0] = 0; acc[1] = 0; acc[2] = 0;
    #pragma unroll
    for (int ql = 0; ql < 15; ql++) {
        int q = kc * 15 + ql;
        bfrag bx = ldf(xt + bl * 248 + ql * 16 + half * 8);
        #pragma unroll
        for (int oct = 0; oct < 3; oct++) {
            bfrag af = ldf(FCWf + ((q * 3 + oct) << 9) + lane * 8);
            acc[oct] = MFMA(af, bx, acc[oct]);
        }
    }
    unsigned short* base = P + (size_t)kc * 96 * BATCH;
    const int b = bg * 128 + bl;
    #pragma unroll
    for (int oct = 0; oct < 3; oct++)
        #pragma unroll
        for (int j = 0; j < 16; j++) {
            int o = oct * 32 + half * 4 + (j >> 2) * 8 + (j & 3);
            base[(size_t)o * BATCH + b] = f2bf(acc[oct][j]);
        }
}

__global__ __launch_bounds__(256) void k_fc_reduce(
        const unsigned short* __restrict__ P, const float* __restrict__ fcb,
        float* __restrict__ out) {
    int j = blockIdx.x * blockDim.x + threadIdx.x;   // j = o*2048 + b, o<72
    int o = j >> 11, b = j & 2047;
    float acc = fcb[o];
    #pragma unroll
    for (int kc = 0; kc < 16; kc++) {
        unsigned u = P[((size_t)kc * 96 + o) * BATCH + b];
        acc += __uint_as_float(u << 16);
    }
    out[b * 72 + o] = acc;
}

// ---------------------------------------------------------------- launch

extern "C" void kernel_launch(void* const* d_in, const int* in_sizes, int n_in,
                              void* d_out, int out_size, void* d_ws, size_t ws_size,
                              hipStream_t stream) {
    const float* x   = (const float*)d_in[0];
    const int*   e32 = (const int*)  d_in[1];
    const float* gw  = (const float*)d_in[2];
    const float* gb  = (const float*)d_in[3];
    const float* cw0 = (const float*)d_in[4];
    const float* cb0 = (const float*)d_in[5];
    const float* dw0 = (const float*)d_in[6];
    const float* db0 = (const float*)d_in[7];
    const float* cw1 = (const float*)d_in[8];
    const float* cb1 = (const float*)d_in[9];
    const float* dw1 = (const float*)d_in[10];
    const float* db1 = (const float*)d_in[11];
    const float* cw2 = (const float*)d_in[12];
    const float* cb2 = (const float*)d_in[13];
    const float* dw2 = (const float*)d_in[14];
    const float* db2 = (const float*)d_in[15];
    const float* fcw = (const float*)d_in[16];
    const float* fcb = (const float*)d_in[17];

    char* w = (char*)d_ws;
    auto alloc = [&](size_t bytes) {
        char* p = w;
        w += (bytes + 255) & ~(size_t)255;
        return p;
    };
    int*            cnt  = (int*)           alloc(N_NODES * 4);
    unsigned short* eidx = (unsigned short*)alloc((size_t)N_NODES * MAXDEG * 2);
    float* w0T  = (float*)alloc(36 * 128 * 4);
    float* d0T  = (float*)alloc(12 * 128 * 4);
    unsigned short* W1f  = (unsigned short*)alloc(196608 * 2);
    unsigned short* D1f  = (unsigned short*)alloc(65536 * 2);
    unsigned short* W2f  = (unsigned short*)alloc(196608 * 2);
    unsigned short* D2f  = (unsigned short*)alloc(65536 * 2);
    unsigned short* FCWf = (unsigned short*)alloc(368640 * 2);
    unsigned short* X3b  = (unsigned short*)alloc((size_t)BATCH * TT * C3 * 2);
    unsigned short* P    = (unsigned short*)alloc((size_t)16 * 96 * BATCH * 2);

    hipMemsetAsync(cnt, 0, N_NODES * 4, stream);
    k_edges_repack<<<1920 + 3488, 256, 0, stream>>>(
        e32, cnt, eidx, cw0, dw0, cw1, dw1, cw2, dw2, fcw,
        w0T, d0T, W1f, D1f, W2f, D2f, FCWf);
    k_tcn012<<<BATCH / 2, 256, 0, stream>>>(
        x, cnt, eidx, gw, gb, w0T, d0T, cb0, db0,
        W1f, D1f, cb1, db1, W2f, D2f, cb2, db2, X3b);
    k_fc_mfma<<<256, 256, 0, stream>>>(X3b, FCWf, P);
    k_fc_reduce<<<72 * BATCH / 256, 256, 0, stream>>>(P, fcb, (float*)d_out);
}

// Round 16
// 138.658 us; speedup vs baseline: 1.1502x; 1.0042x over previous
//
#include <hip/hip_runtime.h>
#include <hip/hip_bf16.h>

#define N_NODES 61440
#define NEDGE   491520
#define BATCH   2048
#define TT      30
#define C1      128
#define C2      512
#define C3      128
#define FCK     3840   // 128*30
#define MAXDEG  40     // Poisson(8) tail: P(deg>40) ~ 1e-11

typedef float floatx16 __attribute__((ext_vector_type(16)));
typedef __bf16 bfrag   __attribute__((ext_vector_type(8)));

static __device__ __forceinline__ unsigned short f2bf(float f) {
    unsigned u = __float_as_uint(f);
    u = u + 0x7fffu + ((u >> 16) & 1u);
    return (unsigned short)(u >> 16);
}
// packed f32x2 -> bf16x2 (RNE, bit-identical to f2bf pair)
static __device__ __forceinline__ unsigned cvtpk(float lo, float hi) {
    unsigned r;
    asm("v_cvt_pk_bf16_f32 %0, %1, %2" : "=v"(r) : "v"(lo), "v"(hi));
    return r;
}
static __device__ __forceinline__ bfrag ldf(const void* p) { return *(const bfrag*)p; }
#define MFMA(a, b, c) __builtin_amdgcn_mfma_f32_32x32x16_bf16(a, b, c, 0, 0, 0)

// ------------------------------------------- edges + weight repack (merged)
__global__ void k_edges_repack(
        const int* __restrict__ e32, int* __restrict__ cnt,
        unsigned short* __restrict__ eidx,
        const float* __restrict__ cw0, const float* __restrict__ dw0,
        const float* __restrict__ cw1, const float* __restrict__ dw1,
        const float* __restrict__ cw2, const float* __restrict__ dw2,
        const float* __restrict__ fcw,
        float* __restrict__ w0T, float* __restrict__ d0T,
        unsigned short* __restrict__ W1f, unsigned short* __restrict__ D1f,
        unsigned short* __restrict__ W2f, unsigned short* __restrict__ D2f,
        unsigned short* __restrict__ FCWf) {
    if (blockIdx.x < 1920) {
        int i = blockIdx.x * 256 + threadIdx.x;
        bool is64 = (e32[1] == 0) & (e32[3] == 0) & (e32[5] == 0) & (e32[7] == 0);
        int s, d;
        if (is64) { s = e32[2 * i]; d = e32[2 * (NEDGE + i)]; }
        else      { s = e32[i];     d = e32[NEDGE + i]; }
        int slot = atomicAdd(&cnt[d], 1);
        if (slot < MAXDEG) eidx[slot * N_NODES + d] = (unsigned short)s;
        return;
    }
    int i = (blockIdx.x - 1920) * 256 + threadIdx.x;
    if (i < 36 * 128) { int oc = i & 127, r = i >> 7; w0T[i] = cw0[oc * 36 + r]; }
    if (i < 12 * 128) { int oc = i & 127, ic = i >> 7; d0T[i] = dw0[oc * 12 + ic]; }
    if (i < 196608) {                       // W1f
        int pos = i & 511, f = i >> 9;
        int lane = pos >> 3, e = pos & 7;
        int oct = f & 15, q = (f >> 4) & 7, tap = f >> 7;
        int oc = oct * 32 + (lane & 31), ic = q * 16 + (lane >> 5) * 8 + e;
        W1f[i] = f2bf(cw1[(oc * 128 + ic) * 3 + tap]);
    } else if (i < 262144) {                // D1f
        int j = i - 196608;
        int pos = j & 511, f = j >> 9;
        int lane = pos >> 3, e = pos & 7;
        int oct = f & 15, q = f >> 4;
        int oc = oct * 32 + (lane & 31), ic = q * 16 + (lane >> 5) * 8 + e;
        D1f[j] = f2bf(dw1[oc * 128 + ic]);
    } else if (i < 458752) {                // W2f
        int j = i - 262144;
        int pos = j & 511, f = j >> 9;
        int lane = pos >> 3, e = pos & 7;
        int oct = f & 3, q = (f >> 2) & 31, tap = f >> 7;
        int oc = oct * 32 + (lane & 31), ic = q * 16 + (lane >> 5) * 8 + e;
        W2f[j] = f2bf(cw2[(oc * 512 + ic) * 3 + tap]);
    } else if (i < 524288) {                // D2f
        int j = i - 458752;
        int pos = j & 511, f = j >> 9;
        int lane = pos >> 3, e = pos & 7;
        int oct = f & 3, q = f >> 2;
        int oc = oct * 32 + (lane & 31), ic = q * 16 + (lane >> 5) * 8 + e;
        D2f[j] = f2bf(dw2[oc * 512 + ic]);
    } else if (i < 892928) {                // FCWf (240*3 frags)
        int j = i - 524288;
        int pos = j & 511, f = j >> 9;
        int lane = pos >> 3, e = pos & 7;
        int oct = f % 3, q = f / 3;
        int o = oct * 32 + (lane & 31);
        int k = q * 16 + (lane >> 5) * 8 + e;
        float v = (o < 72) ? fcw[o * 3840 + (k & 127) * 30 + (k >> 7)] : 0.f;
        FCWf[j] = f2bf(v);
    }
}

// ------------------------------- TCN blocks 0+1+2, fused (GCN gather + MFMA)
// r14: block0 fused as phase 0 (-7 us).  r15: gather 2-way split (-5 us).
// Round-16: gather split 2 -> 4 parts.  Thread = (node, part), part in
// [0,4); each thread covers ALL 12 channels of a quarter-list (240 active,
// chain ne/4 ~ 2).  Loads: 3x float4/neighbor (48 B rows, aligned).  aL
// grows to [60][4][12] = 11.5 KB; phase-0 scratch total 40.6 KB, still
// inside the X2l alias (63.4 KB).  Partials combined in fixed order
// p0+p1+p2+p3 (deterministic, ~1e-7 reorder).
__global__ __launch_bounds__(256, 2) void k_tcn012(
        const float* __restrict__ x, const int* __restrict__ cnt,
        const unsigned short* __restrict__ eidx,
        const float* __restrict__ gw, const float* __restrict__ gb,
        const float* __restrict__ w0T, const float* __restrict__ d0T,
        const float* __restrict__ cb0, const float* __restrict__ db0,
        const unsigned short* __restrict__ W1f, const unsigned short* __restrict__ D1f,
        const float* __restrict__ cb1, const float* __restrict__ db1,
        const unsigned short* __restrict__ W2f, const unsigned short* __restrict__ D2f,
        const float* __restrict__ cb2, const float* __restrict__ db2,
        unsigned short* __restrict__ X3b) {
    __shared__ __align__(16) unsigned short X1l[61 * 136];  // rows 0..59 data, 60 = zeros
    __shared__ __align__(16) unsigned short X2l[61 * 520];
    const int tid  = threadIdx.x;
    const int lane = tid & 63;
    const int wave = tid >> 6;
    const int tcol = lane & 31;
    const int half = lane >> 5;
    const int b0 = blockIdx.x * 2;

    // ---- phase 0 scratch aliased into X2l (first ~41 KB; X2l data region
    // is written only in phase 1, after the phase-0 barrier)
    float* wl  = (float*)X2l;           // 36*128
    float* dl  = wl + 36 * 128;         // 12*128
    float* cbl = dl + 12 * 128;         // 128
    float* dbl = cbl + 128;             // 128
    float* gwl = dbl + 128;             // 144
    float* gbl = gwl + 144;             // 12
    float* aL  = gbl + 12;              // 60*4*12 (node, part)
    float* x0  = aL + 2880;             // 2*30*12

    for (int i = tid; i < 36 * 128; i += 256) wl[i] = w0T[i];
    for (int i = tid; i < 12 * 128; i += 256) dl[i] = d0T[i];
    if (tid < 128) { cbl[tid] = cb0[tid]; dbl[tid] = db0[tid]; }
    if (tid < 144) gwl[tid] = gw[tid];
    if (tid >= 144 && tid < 156) gbl[tid - 144] = gb[tid - 144];

    // ---- phase 0a: gather, 4 threads/node: part p sums quarter-list,
    // all 12 channels per thread
    if (tid < 240) {
        int node = tid % 60;
        int part = tid / 60;            // 0..3
        size_t n = (size_t)b0 * TT + node;
        int ne = cnt[n]; if (ne > MAXDEG) ne = MAXDEG;
        int j0 = (ne * part) >> 2;
        int j1 = (ne * (part + 1)) >> 2;
        float a0 = 0.f, a1 = 0.f, a2 = 0.f, a3 = 0.f;
        float a4 = 0.f, a5 = 0.f, a6 = 0.f, a7 = 0.f;
        float a8 = 0.f, a9 = 0.f, a10 = 0.f, a11 = 0.f;
        int j = j0;
        for (; j + 2 <= j1; j += 2) {
            int s0 = eidx[(j + 0) * N_NODES + n];
            int s1 = eidx[(j + 1) * N_NODES + n];
            float di0 = rsqrtf(1.0f + (float)cnt[s0]);
            float di1 = rsqrtf(1.0f + (float)cnt[s1]);
            const float4* xp0 = (const float4*)(x + (size_t)s0 * 12);
            const float4* xp1 = (const float4*)(x + (size_t)s1 * 12);
            float4 u0 = xp0[0], u1 = xp0[1], u2 = xp0[2];
            float4 v0 = xp1[0], v1 = xp1[1], v2 = xp1[2];
            a0 += di0 * u0.x; a1 += di0 * u0.y; a2  += di0 * u0.z; a3  += di0 * u0.w;
            a4 += di0 * u1.x; a5 += di0 * u1.y; a6  += di0 * u1.z; a7  += di0 * u1.w;
            a8 += di0 * u2.x; a9 += di0 * u2.y; a10 += di0 * u2.z; a11 += di0 * u2.w;
            a0 += di1 * v0.x; a1 += di1 * v0.y; a2  += di1 * v0.z; a3  += di1 * v0.w;
            a4 += di1 * v1.x; a5 += di1 * v1.y; a6  += di1 * v1.z; a7  += di1 * v1.w;
            a8 += di1 * v2.x; a9 += di1 * v2.y; a10 += di1 * v2.z; a11 += di1 * v2.w;
        }
        for (; j < j1; j++) {
            int s = eidx[j * N_NODES + n];
            float di = rsqrtf(1.0f + (float)cnt[s]);
            const float4* xp = (const float4*)(x + (size_t)s * 12);
            float4 u0 = xp[0], u1 = xp[1], u2 = xp[2];
            a0 += di * u0.x; a1 += di * u0.y; a2  += di * u0.z; a3  += di * u0.w;
            a4 += di * u1.x; a5 += di * u1.y; a6  += di * u1.z; a7  += di * u1.w;
            a8 += di * u2.x; a9 += di * u2.y; a10 += di * u2.z; a11 += di * u2.w;
        }
        float* ap = aL + (node * 4 + part) * 12;
        ap[0] = a0; ap[1] = a1; ap[2]  = a2;  ap[3]  = a3;
        ap[4] = a4; ap[5] = a5; ap[6]  = a6;  ap[7]  = a7;
        ap[8] = a8; ap[9] = a9; ap[10] = a10; ap[11] = a11;
    }
    __syncthreads();

    // ---- phase 0b: GCN finalize: u = dinv*(p0+p1+p2+p3) + dinv^2*x
    if (tid < 60) {
        size_t n = (size_t)b0 * TT + tid;
        float di = rsqrtf(1.0f + (float)cnt[n]);
        float d2 = di * di;
        const float4* xp = (const float4*)(x + n * 12);
        const float* p0 = aL + (tid * 4 + 0) * 12;
        const float* p1 = aL + (tid * 4 + 1) * 12;
        const float* p2 = aL + (tid * 4 + 2) * 12;
        const float* p3 = aL + (tid * 4 + 3) * 12;
        float u[12];
        #pragma unroll
        for (int q = 0; q < 3; q++) {
            float4 xv = xp[q];
            u[q*4+0] = di * (((p0[q*4+0] + p1[q*4+0]) + p2[q*4+0]) + p3[q*4+0]) + d2 * xv.x;
            u[q*4+1] = di * (((p0[q*4+1] + p1[q*4+1]) + p2[q*4+1]) + p3[q*4+1]) + d2 * xv.y;
            u[q*4+2] = di * (((p0[q*4+2] + p1[q*4+2]) + p2[q*4+2]) + p3[q*4+2]) + d2 * xv.z;
            u[q*4+3] = di * (((p0[q*4+3] + p1[q*4+3]) + p2[q*4+3]) + p3[q*4+3]) + d2 * xv.w;
        }
        #pragma unroll
        for (int c = 0; c < 12; c++) {
            float acc = gbl[c];
            #pragma unroll
            for (int j = 0; j < 12; j++) acc += u[j] * gwl[c * 12 + j];
            x0[tid * 12 + c] = acc;
        }
    }
    __syncthreads();

    // ---- phase 0c: conv 12->128 + down, straight into X1l
    {
        int oc = tid & 127, bl = tid >> 7;
        float cb = cbl[oc], db = dbl[oc];
        const float* xb = x0 + bl * (TT * 12);
        float conv[TT], res[TT];
        #pragma unroll
        for (int t = 0; t < TT; t++) { conv[t] = 0.f; res[t] = 0.f; }
        #pragma unroll
        for (int ic = 0; ic < 12; ic++) {
            float w0v = wl[(ic * 3 + 0) * 128 + oc];
            float w1v = wl[(ic * 3 + 1) * 128 + oc];
            float w2v = wl[(ic * 3 + 2) * 128 + oc];
            float dv  = dl[ic * 128 + oc];
            #pragma unroll
            for (int t = 0; t < TT; t++) {
                float xv = xb[t * 12 + ic];
                conv[t] += w2v * xv;
                if (t + 1 < TT) conv[t + 1] += w1v * xv;
                if (t + 2 < TT) conv[t + 2] += w0v * xv;
                res[t] += dv * xv;
            }
        }
        #pragma unroll
        for (int t = 0; t < TT; t++) {
            float o1 = fmaxf(conv[t] + cb, 0.f);
            X1l[(bl * 30 + t) * 136 + oc] = f2bf(fmaxf(o1 + res[t] + db, 0.f));
        }
    }
    if (tid < 17) *(uint4*)(X1l + 60 * 136 + tid * 8) = make_uint4(0, 0, 0, 0);
    if (tid < 65) *(uint4*)(X2l + 60 * 520 + tid * 8) = make_uint4(0, 0, 0, 0);

    auto ldw1 = [&](bfrag* dst, int oct, int qc) {
        #pragma unroll
        for (int tap = 0; tap < 3; tap++)
            #pragma unroll
            for (int qq = 0; qq < 4; qq++)
                dst[tap * 4 + qq] =
                    ldf(W1f + (((tap * 8 + qc * 4 + qq) * 16 + oct) << 9) + lane * 8);
        #pragma unroll
        for (int qq = 0; qq < 4; qq++)
            dst[12 + qq] = ldf(D1f + (((qc * 4 + qq) * 16 + oct) << 9) + lane * 8);
    };
    auto ldw2 = [&](bfrag* dst, int oct, int qc) {
        #pragma unroll
        for (int tap = 0; tap < 3; tap++)
            #pragma unroll
            for (int qq = 0; qq < 4; qq++)
                dst[tap * 4 + qq] =
                    ldf(W2f + (((tap * 32 + qc * 4 + qq) * 4 + oct) << 9) + lane * 8);
        #pragma unroll
        for (int qq = 0; qq < 4; qq++)
            dst[12 + qq] = ldf(D2f + (((qc * 4 + qq) * 4 + oct) << 9) + lane * 8);
    };

    // first phase-1 weight prefetch: issued at end of phase 0 (keeps phase-0
    // register peak low; global latency overlaps the barrier)
    bfrag wf[2][16];
    ldw1(wf[0], wave, 0);
    __syncthreads();

    // ---- phase 1: block1 (128->512, k=3 dil=3) + 1x1 down  -> X2l (bf16)
    {
        floatx16 accc[2], accd[2];
        #pragma unroll
        for (int s = 0; s < 8; s++) {
            const int qc = s & 1;
            const int oct = (s >> 1) * 4 + wave;
            if (qc == 0) {
                // bias-folded acc init (channel ocb+j lives at acc[gi*4+j])
                #pragma unroll
                for (int gi = 0; gi < 4; gi++) {
                    int ocb = oct * 32 + half * 4 + gi * 8;
                    float4 cbv = *(const float4*)(cb1 + ocb);
                    float4 dbv = *(const float4*)(db1 + ocb);
                    accc[0][gi*4+0] = cbv.x; accc[0][gi*4+1] = cbv.y;
                    accc[0][gi*4+2] = cbv.z; accc[0][gi*4+3] = cbv.w;
                    accd[0][gi*4+0] = dbv.x; accd[0][gi*4+1] = dbv.y;
                    accd[0][gi*4+2] = dbv.z; accd[0][gi*4+3] = dbv.w;
                    accc[1][gi*4+0] = cbv.x; accc[1][gi*4+1] = cbv.y;
                    accc[1][gi*4+2] = cbv.z; accc[1][gi*4+3] = cbv.w;
                    accd[1][gi*4+0] = dbv.x; accd[1][gi*4+1] = dbv.y;
                    accd[1][gi*4+2] = dbv.z; accd[1][gi*4+3] = dbv.w;
                }
            }
            if (s < 7)
                ldw1(wf[(s + 1) & 1], ((s + 1) >> 1) * 4 + wave, (s + 1) & 1);
            #pragma unroll
            for (int bl = 0; bl < 2; bl++) {
                bfrag bx[3][4];
                #pragma unroll
                for (int si = 0; si < 3; si++) {
                    int trow = tcol - si * 3;
                    const unsigned short* rp = ((unsigned)trow < 30u)
                        ? (X1l + (bl * 30 + trow) * 136) : (X1l + 60 * 136);
                    #pragma unroll
                    for (int qq = 0; qq < 4; qq++)
                        bx[si][qq] = ldf(rp + (qc * 4 + qq) * 16 + half * 8);
                }
                #pragma unroll
                for (int qq = 0; qq < 4; qq++) {
                    accc[bl] = MFMA(wf[s & 1][8 + qq],  bx[0][qq], accc[bl]);
                    accc[bl] = MFMA(wf[s & 1][4 + qq],  bx[1][qq], accc[bl]);
                    accc[bl] = MFMA(wf[s & 1][qq],      bx[2][qq], accc[bl]);
                    accd[bl] = MFMA(wf[s & 1][12 + qq], bx[0][qq], accd[bl]);
                }
            }
            if (qc == 1 && tcol < 30) {
                #pragma unroll
                for (int bl = 0; bl < 2; bl++) {
                    unsigned short* wp = X2l + (bl * 30 + tcol) * 520 + oct * 32 + half * 4;
                    #pragma unroll
                    for (int gi = 0; gi < 4; gi++) {
                        float v0 = fmaxf(fmaxf(accc[bl][gi*4+0], 0.f) + accd[bl][gi*4+0], 0.f);
                        float v1 = fmaxf(fmaxf(accc[bl][gi*4+1], 0.f) + accd[bl][gi*4+1], 0.f);
                        float v2 = fmaxf(fmaxf(accc[bl][gi*4+2], 0.f) + accd[bl][gi*4+2], 0.f);
                        float v3 = fmaxf(fmaxf(accc[bl][gi*4+3], 0.f) + accd[bl][gi*4+3], 0.f);
                        *(uint2*)(wp + gi * 8) = make_uint2(cvtpk(v0, v1), cvtpk(v2, v3));
                    }
                }
            }
        }
    }
    // phase-2 first weight prefetch: issue before the barrier (global->reg)
    bfrag wf2[2][16];
    ldw2(wf2[0], wave, 0);
    __syncthreads();

    // ---- phase 2: block2 (512->128, k=3 dil=9) + 1x1 down -> staged X3
    {
        const int oct = wave;
        floatx16 accc[2], accd[2];
        #pragma unroll
        for (int gi = 0; gi < 4; gi++) {
            int ocb = oct * 32 + half * 4 + gi * 8;
            float4 cbv = *(const float4*)(cb2 + ocb);
            float4 dbv = *(const float4*)(db2 + ocb);
            accc[0][gi*4+0] = cbv.x; accc[0][gi*4+1] = cbv.y;
            accc[0][gi*4+2] = cbv.z; accc[0][gi*4+3] = cbv.w;
            accd[0][gi*4+0] = dbv.x; accd[0][gi*4+1] = dbv.y;
            accd[0][gi*4+2] = dbv.z; accd[0][gi*4+3] = dbv.w;
            accc[1][gi*4+0] = cbv.x; accc[1][gi*4+1] = cbv.y;
            accc[1][gi*4+2] = cbv.z; accc[1][gi*4+3] = cbv.w;
            accd[1][gi*4+0] = dbv.x; accd[1][gi*4+1] = dbv.y;
            accd[1][gi*4+2] = dbv.z; accd[1][gi*4+3] = dbv.w;
        }
        #pragma unroll
        for (int qc = 0; qc < 8; qc++) {
            if (qc < 7) ldw2(wf2[(qc + 1) & 1], oct, qc + 1);
            #pragma unroll
            for (int bl = 0; bl < 2; bl++) {
                bfrag bx[3][4];
                #pragma unroll
                for (int si = 0; si < 3; si++) {
                    int trow = tcol - si * 9;
                    const unsigned short* rp = ((unsigned)trow < 30u)
                        ? (X2l + (bl * 30 + trow) * 520) : (X2l + 60 * 520);
                    #pragma unroll
                    for (int qq = 0; qq < 4; qq++)
                        bx[si][qq] = ldf(rp + (qc * 4 + qq) * 16 + half * 8);
                }
                #pragma unroll
                for (int qq = 0; qq < 4; qq++) {
                    accc[bl] = MFMA(wf2[qc & 1][8 + qq],  bx[0][qq], accc[bl]);
                    accc[bl] = MFMA(wf2[qc & 1][4 + qq],  bx[1][qq], accc[bl]);
                    accc[bl] = MFMA(wf2[qc & 1][qq],      bx[2][qq], accc[bl]);
                    accd[bl] = MFMA(wf2[qc & 1][12 + qq], bx[0][qq], accd[bl]);
                }
            }
        }
        if (tcol < 30) {   // stage into X1l area (free after phase 1)
            #pragma unroll
            for (int bl = 0; bl < 2; bl++) {
                unsigned short* wp = X1l + (bl * 30 + tcol) * 136 + oct * 32 + half * 4;
                #pragma unroll
                for (int gi = 0; gi < 4; gi++) {
                    float v0 = fmaxf(fmaxf(accc[bl][gi*4+0], 0.f) + accd[bl][gi*4+0], 0.f);
                    float v1 = fmaxf(fmaxf(accc[bl][gi*4+1], 0.f) + accd[bl][gi*4+1], 0.f);
                    float v2 = fmaxf(fmaxf(accc[bl][gi*4+2], 0.f) + accd[bl][gi*4+2], 0.f);
                    float v3 = fmaxf(fmaxf(accc[bl][gi*4+3], 0.f) + accd[bl][gi*4+3], 0.f);
                    *(uint2*)(wp + gi * 8) = make_uint2(cvtpk(v0, v1), cvtpk(v2, v3));
                }
            }
        }
    }
    __syncthreads();
    // coalesced flush: 60 rows x 256 B contiguous
    for (int idx = tid; idx < 960; idx += 256) {
        int row = idx >> 4, seg = idx & 15;
        *(uint4*)(X3b + ((size_t)(b0 * 30 + row) << 7) + seg * 8) =
            *(const uint4*)(X1l + row * 136 + seg * 8);
    }
}

// ------------------------------------------------------------- FC (MFMA)
// Deterministic two-stage scheme (bf16 partials, fixed kc reduction order).
__global__ __launch_bounds__(256) void k_fc_mfma(
        const unsigned short* __restrict__ X3b,
        const unsigned short* __restrict__ FCWf,
        unsigned short* __restrict__ P) {
    __shared__ __align__(16) unsigned short xt[128 * 248];   // 240 used + 8 pad
    const int tid  = threadIdx.x;
    const int lane = tid & 63;
    const int wave = tid >> 6;
    const int half = lane >> 5;
    const int bg = blockIdx.x & 15;
    const int kc = blockIdx.x >> 4;

    for (int idx = tid; idx < 128 * 32; idx += 256) {
        int row = idx >> 5, seg = idx & 31;
        if (seg < 30)
            *(uint4*)(xt + row * 248 + seg * 8) =
                *(const uint4*)(X3b + (size_t)(bg * 128 + row) * FCK + kc * 240 + seg * 8);
    }
    __syncthreads();

    const int bl = wave * 32 + (lane & 31);
    floatx16 acc[3];
    acc[0] = 0; acc[1] = 0; acc[2] = 0;
    #pragma unroll
    for (int ql = 0; ql < 15; ql++) {
        int q = kc * 15 + ql;
        bfrag bx = ldf(xt + bl * 248 + ql * 16 + half * 8);
        #pragma unroll
        for (int oct = 0; oct < 3; oct++) {
            bfrag af = ldf(FCWf + ((q * 3 + oct) << 9) + lane * 8);
            acc[oct] = MFMA(af, bx, acc[oct]);
        }
    }
    unsigned short* base = P + (size_t)kc * 96 * BATCH;
    const int b = bg * 128 + bl;
    #pragma unroll
    for (int oct = 0; oct < 3; oct++)
        #pragma unroll
        for (int j = 0; j < 16; j++) {
            int o = oct * 32 + half * 4 + (j >> 2) * 8 + (j & 3);
            base[(size_t)o * BATCH + b] = f2bf(acc[oct][j]);
        }
}

__global__ __launch_bounds__(256) void k_fc_reduce(
        const unsigned short* __restrict__ P, const float* __restrict__ fcb,
        float* __restrict__ out) {
    int j = blockIdx.x * blockDim.x + threadIdx.x;   // j = o*2048 + b, o<72
    int o = j >> 11, b = j & 2047;
    float acc = fcb[o];
    #pragma unroll
    for (int kc = 0; kc < 16; kc++) {
        unsigned u = P[((size_t)kc * 96 + o) * BATCH + b];
        acc += __uint_as_float(u << 16);
    }
    out[b * 72 + o] = acc;
}

// ---------------------------------------------------------------- launch

extern "C" void kernel_launch(void* const* d_in, const int* in_sizes, int n_in,
                              void* d_out, int out_size, void* d_ws, size_t ws_size,
                              hipStream_t stream) {
    const float* x   = (const float*)d_in[0];
    const int*   e32 = (const int*)  d_in[1];
    const float* gw  = (const float*)d_in[2];
    const float* gb  = (const float*)d_in[3];
    const float* cw0 = (const float*)d_in[4];
    const float* cb0 = (const float*)d_in[5];
    const float* dw0 = (const float*)d_in[6];
    const float* db0 = (const float*)d_in[7];
    const float* cw1 = (const float*)d_in[8];
    const float* cb1 = (const float*)d_in[9];
    const float* dw1 = (const float*)d_in[10];
    const float* db1 = (const float*)d_in[11];
    const float* cw2 = (const float*)d_in[12];
    const float* cb2 = (const float*)d_in[13];
    const float* dw2 = (const float*)d_in[14];
    const float* db2 = (const float*)d_in[15];
    const float* fcw = (const float*)d_in[16];
    const float* fcb = (const float*)d_in[17];

    char* w = (char*)d_ws;
    auto alloc = [&](size_t bytes) {
        char* p = w;
        w += (bytes + 255) & ~(size_t)255;
        return p;
    };
    int*            cnt  = (int*)           alloc(N_NODES * 4);
    unsigned short* eidx = (unsigned short*)alloc((size_t)N_NODES * MAXDEG * 2);
    float* w0T  = (float*)alloc(36 * 128 * 4);
    float* d0T  = (float*)alloc(12 * 128 * 4);
    unsigned short* W1f  = (unsigned short*)alloc(196608 * 2);
    unsigned short* D1f  = (unsigned short*)alloc(65536 * 2);
    unsigned short* W2f  = (unsigned short*)alloc(196608 * 2);
    unsigned short* D2f  = (unsigned short*)alloc(65536 * 2);
    unsigned short* FCWf = (unsigned short*)alloc(368640 * 2);
    unsigned short* X3b  = (unsigned short*)alloc((size_t)BATCH * TT * C3 * 2);
    unsigned short* P    = (unsigned short*)alloc((size_t)16 * 96 * BATCH * 2);

    hipMemsetAsync(cnt, 0, N_NODES * 4, stream);
    k_edges_repack<<<1920 + 3488, 256, 0, stream>>>(
        e32, cnt, eidx, cw0, dw0, cw1, dw1, cw2, dw2, fcw,
        w0T, d0T, W1f, D1f, W2f, D2f, FCWf);
    k_tcn012<<<BATCH / 2, 256, 0, stream>>>(
        x, cnt, eidx, gw, gb, w0T, d0T, cb0, db0,
        W1f, D1f, cb1, db1, W2f, D2f, cb2, db2, X3b);
    k_fc_mfma<<<256, 256, 0, stream>>>(X3b, FCWf, P);
    k_fc_reduce<<<72 * BATCH / 256, 256, 0, stream>>>(P, fcb, (float*)d_out);
}